// Round 1
// baseline (1480.998 us; speedup 1.0000x reference)
//
#include <hip/hip_runtime.h>
#include <hip/hip_bf16.h>
#include <math.h>

// Shapes (fixed): B=4, S=512, PH=4096, N=16384, D=1024, G=128, H=8, L=4, FF=4096, GS=32, HD=128
// Workspace use: ~23.7 MB of fp32 scratch.

typedef __bf16 bf16x8_t __attribute__((ext_vector_type(8)));
typedef float  f32x4_t  __attribute__((ext_vector_type(4)));

__device__ __forceinline__ float wredsum(float v){
#pragma unroll
  for (int o = 32; o; o >>= 1) v += __shfl_down(v, o, 64);
  return v;  // valid in lane 0
}

__device__ __forceinline__ bf16x8_t pack8(float4 a, float4 b){
  bf16x8_t v;
  v[0]=(__bf16)a.x; v[1]=(__bf16)a.y; v[2]=(__bf16)a.z; v[3]=(__bf16)a.w;
  v[4]=(__bf16)b.x; v[5]=(__bf16)b.y; v[6]=(__bf16)b.z; v[7]=(__bf16)b.w;
  return v;
}

// ---------------------------------------------------------------- FPS
// One block per batch. Points + running min-dist live in registers.
// Must reproduce jnp.argmax first-index tie-break; exact fp32 arithmetic.
__global__ __launch_bounds__(1024) void fps_kernel(const float* __restrict__ pc,
                                                   float* __restrict__ centers){
  const int b = blockIdx.x;
  const int tid = threadIdx.x;
  const int lane = tid & 63, wv = tid >> 6;
  const float* base = pc + (size_t)b * 16384 * 3;
  float px[16], py[16], pz[16], dist[16];
#pragma unroll
  for (int j = 0; j < 16; ++j){
    int i = tid * 16 + j;
    px[j] = base[i*3]; py[j] = base[i*3+1]; pz[j] = base[i*3+2];
    dist[j] = 1e10f;
  }
  __shared__ float sv[16];
  __shared__ int   si[16];
  __shared__ int   sfar;
  if (tid == 0) sfar = 0;
  __syncthreads();
  for (int t = 0; t < 128; ++t){
    const int far = sfar;
    const float cx = base[far*3], cy = base[far*3+1], cz = base[far*3+2];
    if (tid == 0){
      centers[(b*128+t)*3+0] = cx;
      centers[(b*128+t)*3+1] = cy;
      centers[(b*128+t)*3+2] = cz;
    }
    float bmax = -1.0f; int bidx = 0x7fffffff;
#pragma unroll
    for (int j = 0; j < 16; ++j){
      float dx = __fsub_rn(px[j], cx);
      float dy = __fsub_rn(py[j], cy);
      float dz = __fsub_rn(pz[j], cz);
      float d  = __fadd_rn(__fadd_rn(__fmul_rn(dx,dx), __fmul_rn(dy,dy)), __fmul_rn(dz,dz));
      float nd = fminf(dist[j], d);
      dist[j] = nd;
      if (nd > bmax){ bmax = nd; bidx = tid*16 + j; }
    }
#pragma unroll
    for (int o = 32; o; o >>= 1){
      float ov = __shfl_down(bmax, o, 64);
      int   oi = __shfl_down(bidx, o, 64);
      if (ov > bmax || (ov == bmax && oi < bidx)){ bmax = ov; bidx = oi; }
    }
    if (lane == 0){ sv[wv] = bmax; si[wv] = bidx; }
    __syncthreads();
    if (tid == 0){
      float bv = sv[0]; int bi = si[0];
#pragma unroll
      for (int w = 1; w < 16; ++w)
        if (sv[w] > bv || (sv[w] == bv && si[w] < bi)){ bv = sv[w]; bi = si[w]; }
      sfar = bi;
    }
    __syncthreads();
  }
}

// ------------------------------------------------- mean over S (2-stage)
__global__ __launch_bounds__(256) void partial_kernel(const float* __restrict__ lh,
                                                      float* __restrict__ part){
  const int ph = blockIdx.x*256 + threadIdx.x;   // 16 blocks.x * 256 = 4096
  const int sc = blockIdx.y, b = blockIdx.z;
  const float* p = lh + ((size_t)b*512 + sc*64)*4096 + ph;
  float s0=0,s1=0,s2=0,s3=0;
  for (int j = 0; j < 64; j += 4){
    s0 += p[(size_t)(j+0)*4096];
    s1 += p[(size_t)(j+1)*4096];
    s2 += p[(size_t)(j+2)*4096];
    s3 += p[(size_t)(j+3)*4096];
  }
  part[(size_t)(b*8+sc)*4096 + ph] = (s0+s1)+(s2+s3);
}

__global__ __launch_bounds__(256) void combine_kernel(const float* __restrict__ part,
                                                      float* __restrict__ mlh){
  const int i = blockIdx.x*256 + threadIdx.x;    // 0..16383
  const int b = i >> 12, ph = i & 4095;
  float s = 0;
#pragma unroll
  for (int sc = 0; sc < 8; ++sc) s += part[(size_t)(b*8+sc)*4096 + ph];
  mlh[i] = s * (1.0f/512.0f);
}

// ------------------------------------------------- agg = mean_lh @ fp_w.T + fp_b
__global__ __launch_bounds__(256) void agg_kernel(const float* __restrict__ mlh,
                                                  const float* __restrict__ fpw,
                                                  const float* __restrict__ fpb,
                                                  float* __restrict__ agg){
  const int o = blockIdx.x*4 + (threadIdx.x>>6); // 0..4095 (b*1024 + d)
  const int lane = threadIdx.x & 63;
  const int b = o >> 10, d = o & 1023;
  const float* mp = mlh + b*4096;
  const float* wp = fpw + (size_t)d*4096;
  float s = 0;
#pragma unroll 4
  for (int j = 0; j < 64; ++j){
    int ph = lane + j*64;
    s += mp[ph] * wp[ph];
  }
  s = wredsum(s);
  if (lane == 0) agg[o] = s + fpb[d];
}

// ------------------------------------------------- x0 = agg @ sp_w.T + sp_b  (537 MB read, BW-bound)
__global__ __launch_bounds__(256) void sp_kernel(const float* __restrict__ agg,
                                                 const float* __restrict__ spw,
                                                 const float* __restrict__ spb,
                                                 float* __restrict__ x){
  __shared__ float ag[4*1024];
  for (int i = threadIdx.x; i < 4096; i += 256) ag[i] = agg[i];
  __syncthreads();
  const int wv = threadIdx.x >> 6, lane = threadIdx.x & 63;
  const int rbase = (blockIdx.x*4 + wv) * 8;
  for (int rr = 0; rr < 8; ++rr){
    const int row = rbase + rr;
    const float* wp = spw + (size_t)row*1024 + lane*4;
    const float4 w0 = *(const float4*)(wp      );
    const float4 w1 = *(const float4*)(wp + 256);
    const float4 w2 = *(const float4*)(wp + 512);
    const float4 w3 = *(const float4*)(wp + 768);
    float acc[4];
#pragma unroll
    for (int bb = 0; bb < 4; ++bb){
      const float* gp = &ag[bb*1024 + lane*4];
      const float4 g0 = *(const float4*)(gp      );
      const float4 g1 = *(const float4*)(gp + 256);
      const float4 g2 = *(const float4*)(gp + 512);
      const float4 g3 = *(const float4*)(gp + 768);
      acc[bb] = w0.x*g0.x + w0.y*g0.y + w0.z*g0.z + w0.w*g0.w
              + w1.x*g1.x + w1.y*g1.y + w1.z*g1.z + w1.w*g1.w
              + w2.x*g2.x + w2.y*g2.y + w2.z*g2.z + w2.w*g2.w
              + w3.x*g3.x + w3.y*g3.y + w3.z*g3.z + w3.w*g3.w;
    }
    float a0 = wredsum(acc[0]);
    float a1 = wredsum(acc[1]);
    float a2 = wredsum(acc[2]);
    float a3 = wredsum(acc[3]);
    if (lane == 0){
      const float bias = spb[row];
      x[(size_t)0*131072 + row] = a0 + bias;
      x[(size_t)1*131072 + row] = a1 + bias;
      x[(size_t)2*131072 + row] = a2 + bias;
      x[(size_t)3*131072 + row] = a3 + bias;
    }
  }
}

// ------------------------------------------------- LayerNorm (optionally + pos_embed)
__global__ __launch_bounds__(256) void ln_kernel(const float* __restrict__ x,
                                                 const float* __restrict__ pos,
                                                 const float* __restrict__ w,
                                                 const float* __restrict__ bb,
                                                 float* __restrict__ out){
  const int tok = blockIdx.x, g = tok & 127, t = threadIdx.x;
  const int lane = t & 63, wv = t >> 6;
  const float* xr = x + (size_t)tok*1024;
  float v[4];
#pragma unroll
  for (int j = 0; j < 4; ++j){
    int d = t + j*256;
    float val = xr[d];
    if (pos) val += pos[g*1024 + d];
    v[j] = val;
  }
  __shared__ float r1[4], r2[4];
  float s = wredsum(v[0]+v[1]+v[2]+v[3]);
  if (lane == 0) r1[wv] = s;
  __syncthreads();
  const float mean = (r1[0]+r1[1]+r1[2]+r1[3]) * (1.0f/1024.0f);
  float sq = 0;
#pragma unroll
  for (int j = 0; j < 4; ++j){ float d0 = v[j]-mean; sq += d0*d0; }
  sq = wredsum(sq);
  if (lane == 0) r2[wv] = sq;
  __syncthreads();
  const float var = (r2[0]+r2[1]+r2[2]+r2[3]) * (1.0f/1024.0f);
  const float rs = rsqrtf(var + 1e-5f);
#pragma unroll
  for (int j = 0; j < 4; ++j){
    int d = t + j*256;
    out[(size_t)tok*1024 + d] = (v[j]-mean)*rs*w[d] + bb[d];
  }
}

// ------------------------------------------------- bf16-MFMA GEMM: C = A @ W.T + bias (+epilogue)
// EPI: 0 = bias; 1 = bias + residual R; 2 = bias + exact GELU; 3 = bias + BN + ReLU
template<int EPI>
__global__ __launch_bounds__(256) void gemm64(
  const float* __restrict__ A, const float* __restrict__ W,
  const float* __restrict__ bias, const float* __restrict__ R,
  float* __restrict__ C, int M, int N, int K,
  const float* __restrict__ bnm, const float* __restrict__ bnv,
  const float* __restrict__ bng, const float* __restrict__ bnb)
{
  __shared__ __bf16 As[64*32];
  __shared__ __bf16 Ws[64*32];
  const int n0 = blockIdx.x * 64, m0 = blockIdx.y * 64;
  const int tid = threadIdx.x;
  const int wv = tid >> 6, lane = tid & 63;
  const int wm = wv >> 1, wn = wv & 1;
  const int lr = lane & 15, kb = lane >> 4;
  const int srow = tid >> 2, scb = tid & 3;
  f32x4_t acc[2][2] = {};
  const float* ap = A + (size_t)(m0 + srow) * K + scb * 8;
  const float* wp = W + (size_t)(n0 + srow) * K + scb * 8;
  for (int k0 = 0; k0 < K; k0 += 32){
    __syncthreads();
    const float4 a0 = *(const float4*)(ap + k0);
    const float4 a1 = *(const float4*)(ap + k0 + 4);
    const float4 w0 = *(const float4*)(wp + k0);
    const float4 w1 = *(const float4*)(wp + k0 + 4);
    *(bf16x8_t*)&As[srow*32 + scb*8] = pack8(a0, a1);
    *(bf16x8_t*)&Ws[srow*32 + scb*8] = pack8(w0, w1);
    __syncthreads();
    bf16x8_t af[2], bf[2];
#pragma unroll
    for (int f = 0; f < 2; ++f){
      af[f] = *(bf16x8_t*)&As[(wm*32 + f*16 + lr)*32 + kb*8];
      bf[f] = *(bf16x8_t*)&Ws[(wn*32 + f*16 + lr)*32 + kb*8];
    }
#pragma unroll
    for (int i = 0; i < 2; ++i)
#pragma unroll
      for (int j = 0; j < 2; ++j)
        acc[i][j] = __builtin_amdgcn_mfma_f32_16x16x32_bf16(af[i], bf[j], acc[i][j], 0, 0, 0);
  }
#pragma unroll
  for (int i = 0; i < 2; ++i)
#pragma unroll
    for (int j = 0; j < 2; ++j)
#pragma unroll
      for (int r = 0; r < 4; ++r){
        const int row = m0 + wm*32 + i*16 + (lane>>4)*4 + r;
        const int col = n0 + wn*32 + j*16 + lr;
        float v = acc[i][j][r] + bias[col];
        if (EPI == 1) v += R[(size_t)row*N + col];
        if (EPI == 2) v = v * 0.5f * (1.0f + erff(v * 0.70710678118654752440f));
        if (EPI == 3){
          v = (v - bnm[col]) * rsqrtf(bnv[col] + 1e-5f) * bng[col] + bnb[col];
          v = fmaxf(v, 0.0f);
        }
        C[(size_t)row*N + col] = v;
      }
}

// ------------------------------------------------- attention: S = scale * Q @ K.T   (one block per (b,h))
__global__ __launch_bounds__(256) void attn_qk(const float* __restrict__ qkv,
                                               float* __restrict__ S){
  const int bh = blockIdx.x, b = bh >> 3, h = bh & 7;
  const int tid = threadIdx.x, wv = tid>>6, lane = tid&63;
  const int wm = wv>>1, wn = wv&1;
  const int lr = lane&15, kb = lane>>4;
  const float* qbase = qkv + (size_t)(b*128)*3072 + h*128;
  const float* kbase = qbase + 1024;
  f32x4_t acc[4][4] = {};
#pragma unroll
  for (int ks = 0; ks < 4; ++ks){
    bf16x8_t aq[4], bk[4];
#pragma unroll
    for (int f = 0; f < 4; ++f){
      const float* p = qbase + (size_t)(wm*64 + f*16 + lr)*3072 + ks*32 + kb*8;
      aq[f] = pack8(*(const float4*)p, *(const float4*)(p+4));
      const float* p2 = kbase + (size_t)(wn*64 + f*16 + lr)*3072 + ks*32 + kb*8;
      bk[f] = pack8(*(const float4*)p2, *(const float4*)(p2+4));
    }
#pragma unroll
    for (int i = 0; i < 4; ++i)
#pragma unroll
      for (int j = 0; j < 4; ++j)
        acc[i][j] = __builtin_amdgcn_mfma_f32_16x16x32_bf16(aq[i], bk[j], acc[i][j], 0, 0, 0);
  }
  const float scale = 0.088388347648318447f;  // 1/sqrt(128)
  float* sb = S + (size_t)bh*16384;
#pragma unroll
  for (int i = 0; i < 4; ++i)
#pragma unroll
    for (int j = 0; j < 4; ++j)
#pragma unroll
      for (int r = 0; r < 4; ++r){
        const int row = wm*64 + i*16 + (lane>>4)*4 + r;
        const int col = wn*64 + j*16 + lr;
        sb[row*128 + col] = acc[i][j][r] * scale;
      }
}

// ------------------------------------------------- softmax rows of S (in place), one wave per row
__global__ __launch_bounds__(256) void attn_sm(float* __restrict__ S){
  const int row = blockIdx.x*4 + (threadIdx.x>>6);  // 0..4095
  const int lane = threadIdx.x & 63;
  float* p = S + (size_t)row*128;
  float v0 = p[lane], v1 = p[lane+64];
  float m = fmaxf(v0, v1);
#pragma unroll
  for (int o = 1; o < 64; o <<= 1) m = fmaxf(m, __shfl_xor(m, o, 64));
  float e0 = expf(v0 - m), e1 = expf(v1 - m);
  float s = e0 + e1;
#pragma unroll
  for (int o = 1; o < 64; o <<= 1) s += __shfl_xor(s, o, 64);
  const float inv = 1.0f / s;
  p[lane] = e0*inv; p[lane+64] = e1*inv;
}

// ------------------------------------------------- O = P @ V  (V^T staged in swizzled LDS)
__global__ __launch_bounds__(256) void attn_pv(const float* __restrict__ P,
                                               const float* __restrict__ qkv,
                                               float* __restrict__ O){
  const int bh = blockIdx.x, b = bh>>3, h = bh&7;
  const int tid = threadIdx.x, wv = tid>>6, lane = tid&63;
  const int wm = wv>>1, wn = wv&1, lr = lane&15, kb = lane>>4;
  __shared__ __bf16 vt[128*128];
  {
    const int n = tid >> 1, kh = tid & 1;
    const float* vbase = qkv + (size_t)(b*128)*3072 + 2048 + h*128 + n;
#pragma unroll
    for (int jb = 0; jb < 8; ++jb){
      bf16x8_t pk;
#pragma unroll
      for (int e = 0; e < 8; ++e){
        int k = kh*64 + jb*8 + e;
        pk[e] = (__bf16)vbase[(size_t)k*3072];
      }
      int cb = kh*8 + jb;
      *(bf16x8_t*)&vt[n*128 + ((cb ^ (n&7)) * 8)] = pk;
    }
  }
  __syncthreads();
  const float* pb = P + (size_t)bh*16384;
  f32x4_t acc[4][4] = {};
#pragma unroll
  for (int ks = 0; ks < 4; ++ks){
    bf16x8_t ap[4], bv[4];
#pragma unroll
    for (int f = 0; f < 4; ++f){
      const float* p = pb + (size_t)(wm*64 + f*16 + lr)*128 + ks*32 + kb*8;
      ap[f] = pack8(*(const float4*)p, *(const float4*)(p+4));
      const int rowv = wn*64 + f*16 + lr;
      const int cb = ks*4 + kb;
      bv[f] = *(bf16x8_t*)&vt[rowv*128 + ((cb ^ (rowv&7)) * 8)];
    }
#pragma unroll
    for (int i = 0; i < 4; ++i)
#pragma unroll
      for (int j = 0; j < 4; ++j)
        acc[i][j] = __builtin_amdgcn_mfma_f32_16x16x32_bf16(ap[i], bv[j], acc[i][j], 0, 0, 0);
  }
#pragma unroll
  for (int i = 0; i < 4; ++i)
#pragma unroll
    for (int j = 0; j < 4; ++j)
#pragma unroll
      for (int r = 0; r < 4; ++r){
        const int row = wm*64 + i*16 + (lane>>4)*4 + r;
        const int col = wn*64 + j*16 + lr;
        O[(size_t)(b*128+row)*1024 + h*128 + col] = acc[i][j][r];
      }
}

// ------------------------------------------------- final head: out = h @ c2_w.T + c2_b + centers
__global__ __launch_bounds__(256) void c2_kernel(const float* __restrict__ hb,
                                                 const float* __restrict__ w,
                                                 const float* __restrict__ bb,
                                                 const float* __restrict__ centers,
                                                 float* __restrict__ out){
  const int o = blockIdx.x*4 + (threadIdx.x>>6);  // 0..49151
  const int lane = threadIdx.x & 63;
  const int tok = o / 96, n = o % 96;
  const float* hp = hb + (size_t)tok*1024;
  const float* wp = w + (size_t)n*1024;
  float s = 0;
#pragma unroll 4
  for (int j = 0; j < 16; ++j){
    int k = lane + j*64;
    s += hp[k] * wp[k];
  }
  s = wredsum(s);
  if (lane == 0) out[o] = s + bb[n] + centers[tok*3 + (n % 3)];
}

// =================================================================
extern "C" void kernel_launch(void* const* d_in, const int* in_sizes, int n_in,
                              void* d_out, int out_size, void* d_ws, size_t ws_size,
                              hipStream_t stream){
  const float* lh   = (const float*)d_in[0];
  const float* pc   = (const float*)d_in[1];
  const float* fpw  = (const float*)d_in[2];
  const float* fpb  = (const float*)d_in[3];
  const float* spw  = (const float*)d_in[4];
  const float* spb  = (const float*)d_in[5];
  const float* pos  = (const float*)d_in[6];
  const float* ln1w = (const float*)d_in[7];
  const float* ln1b = (const float*)d_in[8];
  const float* inw  = (const float*)d_in[9];
  const float* inb  = (const float*)d_in[10];
  const float* outw = (const float*)d_in[11];
  const float* outb = (const float*)d_in[12];
  const float* ln2w = (const float*)d_in[13];
  const float* ln2b = (const float*)d_in[14];
  const float* w1   = (const float*)d_in[15];
  const float* b1   = (const float*)d_in[16];
  const float* w2   = (const float*)d_in[17];
  const float* b2   = (const float*)d_in[18];
  const float* c1w  = (const float*)d_in[19];
  const float* c1b  = (const float*)d_in[20];
  const float* bng  = (const float*)d_in[21];
  const float* bnbt = (const float*)d_in[22];
  const float* bnm  = (const float*)d_in[23];
  const float* bnv  = (const float*)d_in[24];
  const float* c2w  = (const float*)d_in[25];
  const float* c2b  = (const float*)d_in[26];
  float* out = (float*)d_out;
  float* ws  = (float*)d_ws;

  float* Sbuf = ws;               // 524288  (32*128*128 attn scores/probs)
  float* part = Sbuf + 524288;    // 131072  (B*8*PH partial sums)
  float* mlh  = part + 131072;    // 16384   (B*PH mean)
  float* agg  = mlh  + 16384;     // 4096    (B*D)
  float* x    = agg  + 4096;      // 524288  (residual stream, B*G x D)
  float* xn   = x    + 524288;    // 524288  (LN output)
  float* qkv  = xn   + 524288;    // 1572864 (B*G x 3D)
  float* obuf = qkv  + 1572864;   // 524288  (attn out)
  float* hbuf = obuf + 524288;    // 2097152 (MLP hidden / c1 hidden)
  float* cent = hbuf + 2097152;   // 1536    (B*G*3 centers)

  fps_kernel<<<4, 1024, 0, stream>>>(pc, cent);
  partial_kernel<<<dim3(16,8,4), 256, 0, stream>>>(lh, part);
  combine_kernel<<<64, 256, 0, stream>>>(part, mlh);
  agg_kernel<<<1024, 256, 0, stream>>>(mlh, fpw, fpb, agg);
  sp_kernel<<<4096, 256, 0, stream>>>(agg, spw, spb, x);

  for (int l = 0; l < 4; ++l){
    ln_kernel<<<512, 256, 0, stream>>>(x, pos, ln1w + l*1024, ln1b + l*1024, xn);
    gemm64<0><<<dim3(48,8), 256, 0, stream>>>(xn, inw + (size_t)l*3072*1024, inb + l*3072,
                                              nullptr, qkv, 512, 3072, 1024,
                                              nullptr, nullptr, nullptr, nullptr);
    attn_qk<<<32, 256, 0, stream>>>(qkv, Sbuf);
    attn_sm<<<1024, 256, 0, stream>>>(Sbuf);
    attn_pv<<<32, 256, 0, stream>>>(Sbuf, qkv, obuf);
    gemm64<1><<<dim3(16,8), 256, 0, stream>>>(obuf, outw + (size_t)l*1024*1024, outb + l*1024,
                                              x, x, 512, 1024, 1024,
                                              nullptr, nullptr, nullptr, nullptr);
    ln_kernel<<<512, 256, 0, stream>>>(x, nullptr, ln2w + l*1024, ln2b + l*1024, xn);
    gemm64<2><<<dim3(64,8), 256, 0, stream>>>(xn, w1 + (size_t)l*4096*1024, b1 + l*4096,
                                              nullptr, hbuf, 512, 4096, 1024,
                                              nullptr, nullptr, nullptr, nullptr);
    gemm64<1><<<dim3(16,8), 256, 0, stream>>>(hbuf, w2 + (size_t)l*1024*4096, b2 + l*1024,
                                              x, x, 512, 1024, 4096,
                                              nullptr, nullptr, nullptr, nullptr);
  }

  gemm64<3><<<dim3(16,8), 256, 0, stream>>>(x, c1w, c1b, nullptr, hbuf, 512, 1024, 1024,
                                            bnm, bnv, bng, bnbt);
  c2_kernel<<<12288, 256, 0, stream>>>(hbuf, c2w, c2b, cent, out);
}

// Round 2
// 1413.281 us; speedup vs baseline: 1.0479x; 1.0479x over previous
//
#include <hip/hip_runtime.h>
#include <hip/hip_bf16.h>
#include <math.h>

// Shapes (fixed): B=4, S=512, PH=4096, N=16384, D=1024, G=128, H=8, L=4, FF=4096, GS=32, HD=128

typedef __bf16 bf16x8_t __attribute__((ext_vector_type(8)));
typedef float  f32x4_t  __attribute__((ext_vector_type(4)));

__device__ __forceinline__ float wredsum(float v){
#pragma unroll
  for (int o = 32; o; o >>= 1) v += __shfl_down(v, o, 64);
  return v;  // valid in lane 0
}

__device__ __forceinline__ bf16x8_t pack8(float4 a, float4 b){
  bf16x8_t v;
  v[0]=(__bf16)a.x; v[1]=(__bf16)a.y; v[2]=(__bf16)a.z; v[3]=(__bf16)a.w;
  v[4]=(__bf16)b.x; v[5]=(__bf16)b.y; v[6]=(__bf16)b.z; v[7]=(__bf16)b.w;
  return v;
}

// ---------------------------------------------------------------- FPS
// One block per batch, 1024 threads, 16 points/thread in registers.
// Latency-optimized: centroid coords travel through the reduction payload
// (no global loads in the dependent chain), wave0 does the cross-wave
// reduce (no serial tid0 scan), 2 barriers/iteration.
// Exact fp32 arithmetic + first-index argmax tie-break to match jnp.
__global__ __launch_bounds__(1024) void fps_kernel(const float* __restrict__ pc,
                                                   float* __restrict__ centers){
  const int b = blockIdx.x;
  const int tid = threadIdx.x;
  const int lane = tid & 63, wv = tid >> 6;
  const float* base = pc + (size_t)b * 16384 * 3;
  float px[16], py[16], pz[16], dist[16];
  {
    union { float4 v4[12]; float f[48]; } u;
    const float4* src = (const float4*)(base + tid * 48);
#pragma unroll
    for (int q = 0; q < 12; ++q) u.v4[q] = src[q];
#pragma unroll
    for (int j = 0; j < 16; ++j){
      px[j] = u.f[j*3]; py[j] = u.f[j*3+1]; pz[j] = u.f[j*3+2];
      dist[j] = 1e10f;
    }
  }
  __shared__ float sred[5][16];
  __shared__ float sbc[3];
  // centroid 0 = point 0 (uniform broadcast load, once)
  float cx = base[0], cy = base[1], cz = base[2];
  for (int t = 0; t < 128; ++t){
    if (tid == 0){
      centers[(b*128+t)*3+0] = cx;
      centers[(b*128+t)*3+1] = cy;
      centers[(b*128+t)*3+2] = cz;
    }
    float bmax = -1.0f; int bidx = 0x7fffffff;
    float bx = 0.f, by = 0.f, bz = 0.f;
#pragma unroll
    for (int j = 0; j < 16; ++j){
      float dx = __fsub_rn(px[j], cx);
      float dy = __fsub_rn(py[j], cy);
      float dz = __fsub_rn(pz[j], cz);
      float d  = __fadd_rn(__fadd_rn(__fmul_rn(dx,dx), __fmul_rn(dy,dy)), __fmul_rn(dz,dz));
      float nd = fminf(dist[j], d);
      dist[j] = nd;
      if (nd > bmax){ bmax = nd; bidx = tid*16 + j; bx = px[j]; by = py[j]; bz = pz[j]; }
    }
    // wave-level argmax (payload: val, idx, x, y, z)
#pragma unroll
    for (int o = 32; o; o >>= 1){
      float ov = __shfl_down(bmax, o, 64);
      int   oi = __shfl_down(bidx, o, 64);
      float ox = __shfl_down(bx, o, 64);
      float oy = __shfl_down(by, o, 64);
      float oz = __shfl_down(bz, o, 64);
      if (ov > bmax || (ov == bmax && oi < bidx)){
        bmax = ov; bidx = oi; bx = ox; by = oy; bz = oz;
      }
    }
    if (lane == 0){
      sred[0][wv] = bmax;
      sred[1][wv] = __int_as_float(bidx);
      sred[2][wv] = bx;
      sred[3][wv] = by;
      sred[4][wv] = bz;
    }
    __syncthreads();
    if (wv == 0){
      float v  = (lane < 16) ? sred[0][lane] : -2.0f;
      int   i2 = (lane < 16) ? __float_as_int(sred[1][lane]) : 0x7fffffff;
      float x2 = (lane < 16) ? sred[2][lane] : 0.f;
      float y2 = (lane < 16) ? sred[3][lane] : 0.f;
      float z2 = (lane < 16) ? sred[4][lane] : 0.f;
#pragma unroll
      for (int o = 8; o; o >>= 1){
        float ov = __shfl_down(v,  o, 64);
        int   oi = __shfl_down(i2, o, 64);
        float ox = __shfl_down(x2, o, 64);
        float oy = __shfl_down(y2, o, 64);
        float oz = __shfl_down(z2, o, 64);
        if (ov > v || (ov == v && oi < i2)){
          v = ov; i2 = oi; x2 = ox; y2 = oy; z2 = oz;
        }
      }
      if (lane == 0){ sbc[0] = x2; sbc[1] = y2; sbc[2] = z2; }
    }
    __syncthreads();
    cx = sbc[0]; cy = sbc[1]; cz = sbc[2];
  }
}

// ------------------------------------------------- mean over S (2-stage)
__global__ __launch_bounds__(256) void partial_kernel(const float* __restrict__ lh,
                                                      float* __restrict__ part){
  const int ph = blockIdx.x*256 + threadIdx.x;   // 16 blocks.x * 256 = 4096
  const int sc = blockIdx.y, b = blockIdx.z;
  const float* p = lh + ((size_t)b*512 + sc*64)*4096 + ph;
  float s0=0,s1=0,s2=0,s3=0;
  for (int j = 0; j < 64; j += 4){
    s0 += p[(size_t)(j+0)*4096];
    s1 += p[(size_t)(j+1)*4096];
    s2 += p[(size_t)(j+2)*4096];
    s3 += p[(size_t)(j+3)*4096];
  }
  part[(size_t)(b*8+sc)*4096 + ph] = (s0+s1)+(s2+s3);
}

__global__ __launch_bounds__(256) void combine_kernel(const float* __restrict__ part,
                                                      float* __restrict__ mlh){
  const int i = blockIdx.x*256 + threadIdx.x;    // 0..16383
  const int b = i >> 12, ph = i & 4095;
  float s = 0;
#pragma unroll
  for (int sc = 0; sc < 8; ++sc) s += part[(size_t)(b*8+sc)*4096 + ph];
  mlh[i] = s * (1.0f/512.0f);
}

// ------------------------------------------------- agg = mean_lh @ fp_w.T + fp_b
__global__ __launch_bounds__(256) void agg_kernel(const float* __restrict__ mlh,
                                                  const float* __restrict__ fpw,
                                                  const float* __restrict__ fpb,
                                                  float* __restrict__ agg){
  const int o = blockIdx.x*4 + (threadIdx.x>>6); // 0..4095 (b*1024 + d)
  const int lane = threadIdx.x & 63;
  const int b = o >> 10, d = o & 1023;
  const float* mp = mlh + b*4096;
  const float* wp = fpw + (size_t)d*4096;
  float s = 0;
#pragma unroll 4
  for (int j = 0; j < 64; ++j){
    int ph = lane + j*64;
    s += mp[ph] * wp[ph];
  }
  s = wredsum(s);
  if (lane == 0) agg[o] = s + fpb[d];
}

// ------------------------------------------------- x0 = agg @ sp_w.T + sp_b  (537 MB read, BW-bound)
__global__ __launch_bounds__(256) void sp_kernel(const float* __restrict__ agg,
                                                 const float* __restrict__ spw,
                                                 const float* __restrict__ spb,
                                                 float* __restrict__ x){
  __shared__ float ag[4*1024];
  for (int i = threadIdx.x; i < 4096; i += 256) ag[i] = agg[i];
  __syncthreads();
  const int wv = threadIdx.x >> 6, lane = threadIdx.x & 63;
  const int rbase = (blockIdx.x*4 + wv) * 8;
  for (int rr = 0; rr < 8; ++rr){
    const int row = rbase + rr;
    const float* wp = spw + (size_t)row*1024 + lane*4;
    const float4 w0 = *(const float4*)(wp      );
    const float4 w1 = *(const float4*)(wp + 256);
    const float4 w2 = *(const float4*)(wp + 512);
    const float4 w3 = *(const float4*)(wp + 768);
    float acc[4];
#pragma unroll
    for (int bb = 0; bb < 4; ++bb){
      const float* gp = &ag[bb*1024 + lane*4];
      const float4 g0 = *(const float4*)(gp      );
      const float4 g1 = *(const float4*)(gp + 256);
      const float4 g2 = *(const float4*)(gp + 512);
      const float4 g3 = *(const float4*)(gp + 768);
      acc[bb] = w0.x*g0.x + w0.y*g0.y + w0.z*g0.z + w0.w*g0.w
              + w1.x*g1.x + w1.y*g1.y + w1.z*g1.z + w1.w*g1.w
              + w2.x*g2.x + w2.y*g2.y + w2.z*g2.z + w2.w*g2.w
              + w3.x*g3.x + w3.y*g3.y + w3.z*g3.z + w3.w*g3.w;
    }
    float a0 = wredsum(acc[0]);
    float a1 = wredsum(acc[1]);
    float a2 = wredsum(acc[2]);
    float a3 = wredsum(acc[3]);
    if (lane == 0){
      const float bias = spb[row];
      x[(size_t)0*131072 + row] = a0 + bias;
      x[(size_t)1*131072 + row] = a1 + bias;
      x[(size_t)2*131072 + row] = a2 + bias;
      x[(size_t)3*131072 + row] = a3 + bias;
    }
  }
}

// ------------------------------------------------- LayerNorm (optionally + pos_embed)
__global__ __launch_bounds__(256) void ln_kernel(const float* __restrict__ x,
                                                 const float* __restrict__ pos,
                                                 const float* __restrict__ w,
                                                 const float* __restrict__ bb,
                                                 float* __restrict__ out){
  const int tok = blockIdx.x, g = tok & 127, t = threadIdx.x;
  const int lane = t & 63, wv = t >> 6;
  const float* xr = x + (size_t)tok*1024;
  float v[4];
#pragma unroll
  for (int j = 0; j < 4; ++j){
    int d = t + j*256;
    float val = xr[d];
    if (pos) val += pos[g*1024 + d];
    v[j] = val;
  }
  __shared__ float r1[4], r2[4];
  float s = wredsum(v[0]+v[1]+v[2]+v[3]);
  if (lane == 0) r1[wv] = s;
  __syncthreads();
  const float mean = (r1[0]+r1[1]+r1[2]+r1[3]) * (1.0f/1024.0f);
  float sq = 0;
#pragma unroll
  for (int j = 0; j < 4; ++j){ float d0 = v[j]-mean; sq += d0*d0; }
  sq = wredsum(sq);
  if (lane == 0) r2[wv] = sq;
  __syncthreads();
  const float var = (r2[0]+r2[1]+r2[2]+r2[3]) * (1.0f/1024.0f);
  const float rs = rsqrtf(var + 1e-5f);
#pragma unroll
  for (int j = 0; j < 4; ++j){
    int d = t + j*256;
    out[(size_t)tok*1024 + d] = (v[j]-mean)*rs*w[d] + bb[d];
  }
}

// ------------------------------------------------- bf16-MFMA GEMM: C = A @ W.T + bias (+epilogue)
// EPI: 0 = bias; 1 = bias + residual R; 2 = bias + exact GELU; 3 = bias + BN + ReLU
template<int EPI>
__global__ __launch_bounds__(256) void gemm64(
  const float* __restrict__ A, const float* __restrict__ W,
  const float* __restrict__ bias, const float* __restrict__ R,
  float* __restrict__ C, int M, int N, int K,
  const float* __restrict__ bnm, const float* __restrict__ bnv,
  const float* __restrict__ bng, const float* __restrict__ bnb)
{
  __shared__ __bf16 As[64*32];
  __shared__ __bf16 Ws[64*32];
  const int n0 = blockIdx.x * 64, m0 = blockIdx.y * 64;
  const int tid = threadIdx.x;
  const int wv = tid >> 6, lane = tid & 63;
  const int wm = wv >> 1, wn = wv & 1;
  const int lr = lane & 15, kb = lane >> 4;
  const int srow = tid >> 2, scb = tid & 3;
  f32x4_t acc[2][2] = {};
  const float* ap = A + (size_t)(m0 + srow) * K + scb * 8;
  const float* wp = W + (size_t)(n0 + srow) * K + scb * 8;
  for (int k0 = 0; k0 < K; k0 += 32){
    __syncthreads();
    const float4 a0 = *(const float4*)(ap + k0);
    const float4 a1 = *(const float4*)(ap + k0 + 4);
    const float4 w0 = *(const float4*)(wp + k0);
    const float4 w1 = *(const float4*)(wp + k0 + 4);
    *(bf16x8_t*)&As[srow*32 + scb*8] = pack8(a0, a1);
    *(bf16x8_t*)&Ws[srow*32 + scb*8] = pack8(w0, w1);
    __syncthreads();
    bf16x8_t af[2], bf[2];
#pragma unroll
    for (int f = 0; f < 2; ++f){
      af[f] = *(bf16x8_t*)&As[(wm*32 + f*16 + lr)*32 + kb*8];
      bf[f] = *(bf16x8_t*)&Ws[(wn*32 + f*16 + lr)*32 + kb*8];
    }
#pragma unroll
    for (int i = 0; i < 2; ++i)
#pragma unroll
      for (int j = 0; j < 2; ++j)
        acc[i][j] = __builtin_amdgcn_mfma_f32_16x16x32_bf16(af[i], bf[j], acc[i][j], 0, 0, 0);
  }
#pragma unroll
  for (int i = 0; i < 2; ++i)
#pragma unroll
    for (int j = 0; j < 2; ++j)
#pragma unroll
      for (int r = 0; r < 4; ++r){
        const int row = m0 + wm*32 + i*16 + (lane>>4)*4 + r;
        const int col = n0 + wn*32 + j*16 + lr;
        float v = acc[i][j][r] + bias[col];
        if (EPI == 1) v += R[(size_t)row*N + col];
        if (EPI == 2) v = v * 0.5f * (1.0f + erff(v * 0.70710678118654752440f));
        if (EPI == 3){
          v = (v - bnm[col]) * rsqrtf(bnv[col] + 1e-5f) * bng[col] + bnb[col];
          v = fmaxf(v, 0.0f);
        }
        C[(size_t)row*N + col] = v;
      }
}

// ------------------------------------------------- attention: S = scale * Q @ K.T   (one block per (b,h))
__global__ __launch_bounds__(256) void attn_qk(const float* __restrict__ qkv,
                                               float* __restrict__ S){
  const int bh = blockIdx.x, b = bh >> 3, h = bh & 7;
  const int tid = threadIdx.x, wv = tid>>6, lane = tid&63;
  const int wm = wv>>1, wn = wv&1;
  const int lr = lane&15, kb = lane>>4;
  const float* qbase = qkv + (size_t)(b*128)*3072 + h*128;
  const float* kbase = qbase + 1024;
  f32x4_t acc[4][4] = {};
#pragma unroll
  for (int ks = 0; ks < 4; ++ks){
    bf16x8_t aq[4], bk[4];
#pragma unroll
    for (int f = 0; f < 4; ++f){
      const float* p = qbase + (size_t)(wm*64 + f*16 + lr)*3072 + ks*32 + kb*8;
      aq[f] = pack8(*(const float4*)p, *(const float4*)(p+4));
      const float* p2 = kbase + (size_t)(wn*64 + f*16 + lr)*3072 + ks*32 + kb*8;
      bk[f] = pack8(*(const float4*)p2, *(const float4*)(p2+4));
    }
#pragma unroll
    for (int i = 0; i < 4; ++i)
#pragma unroll
      for (int j = 0; j < 4; ++j)
        acc[i][j] = __builtin_amdgcn_mfma_f32_16x16x32_bf16(aq[i], bk[j], acc[i][j], 0, 0, 0);
  }
  const float scale = 0.088388347648318447f;  // 1/sqrt(128)
  float* sb = S + (size_t)bh*16384;
#pragma unroll
  for (int i = 0; i < 4; ++i)
#pragma unroll
    for (int j = 0; j < 4; ++j)
#pragma unroll
      for (int r = 0; r < 4; ++r){
        const int row = wm*64 + i*16 + (lane>>4)*4 + r;
        const int col = wn*64 + j*16 + lr;
        sb[row*128 + col] = acc[i][j][r] * scale;
      }
}

// ------------------------------------------------- softmax rows of S (in place), one wave per row
__global__ __launch_bounds__(256) void attn_sm(float* __restrict__ S){
  const int row = blockIdx.x*4 + (threadIdx.x>>6);  // 0..4095
  const int lane = threadIdx.x & 63;
  float* p = S + (size_t)row*128;
  float v0 = p[lane], v1 = p[lane+64];
  float m = fmaxf(v0, v1);
#pragma unroll
  for (int o = 1; o < 64; o <<= 1) m = fmaxf(m, __shfl_xor(m, o, 64));
  float e0 = expf(v0 - m), e1 = expf(v1 - m);
  float s = e0 + e1;
#pragma unroll
  for (int o = 1; o < 64; o <<= 1) s += __shfl_xor(s, o, 64);
  const float inv = 1.0f / s;
  p[lane] = e0*inv; p[lane+64] = e1*inv;
}

// ------------------------------------------------- O = P @ V  (V^T staged in swizzled LDS)
__global__ __launch_bounds__(256) void attn_pv(const float* __restrict__ P,
                                               const float* __restrict__ qkv,
                                               float* __restrict__ O){
  const int bh = blockIdx.x, b = bh>>3, h = bh&7;
  const int tid = threadIdx.x, wv = tid>>6, lane = tid&63;
  const int wm = wv>>1, wn = wv&1, lr = lane&15, kb = lane>>4;
  __shared__ __bf16 vt[128*128];
  {
    const int n = tid >> 1, kh = tid & 1;
    const float* vbase = qkv + (size_t)(b*128)*3072 + 2048 + h*128 + n;
#pragma unroll
    for (int jb = 0; jb < 8; ++jb){
      bf16x8_t pk;
#pragma unroll
      for (int e = 0; e < 8; ++e){
        int k = kh*64 + jb*8 + e;
        pk[e] = (__bf16)vbase[(size_t)k*3072];
      }
      int cb = kh*8 + jb;
      *(bf16x8_t*)&vt[n*128 + ((cb ^ (n&7)) * 8)] = pk;
    }
  }
  __syncthreads();
  const float* pb = P + (size_t)bh*16384;
  f32x4_t acc[4][4] = {};
#pragma unroll
  for (int ks = 0; ks < 4; ++ks){
    bf16x8_t ap[4], bv[4];
#pragma unroll
    for (int f = 0; f < 4; ++f){
      const float* p = pb + (size_t)(wm*64 + f*16 + lr)*128 + ks*32 + kb*8;
      ap[f] = pack8(*(const float4*)p, *(const float4*)(p+4));
      const int rowv = wn*64 + f*16 + lr;
      const int cb = ks*4 + kb;
      bv[f] = *(bf16x8_t*)&vt[rowv*128 + ((cb ^ (rowv&7)) * 8)];
    }
#pragma unroll
    for (int i = 0; i < 4; ++i)
#pragma unroll
      for (int j = 0; j < 4; ++j)
        acc[i][j] = __builtin_amdgcn_mfma_f32_16x16x32_bf16(ap[i], bv[j], acc[i][j], 0, 0, 0);
  }
#pragma unroll
  for (int i = 0; i < 4; ++i)
#pragma unroll
    for (int j = 0; j < 4; ++j)
#pragma unroll
      for (int r = 0; r < 4; ++r){
        const int row = wm*64 + i*16 + (lane>>4)*4 + r;
        const int col = wn*64 + j*16 + lr;
        O[(size_t)(b*128+row)*1024 + h*128 + col] = acc[i][j][r];
      }
}

// ------------------------------------------------- final head: out = h @ c2_w.T + c2_b + centers
__global__ __launch_bounds__(256) void c2_kernel(const float* __restrict__ hb,
                                                 const float* __restrict__ w,
                                                 const float* __restrict__ bb,
                                                 const float* __restrict__ centers,
                                                 float* __restrict__ out){
  const int o = blockIdx.x*4 + (threadIdx.x>>6);  // 0..49151
  const int lane = threadIdx.x & 63;
  const int tok = o / 96, n = o % 96;
  const float* hp = hb + (size_t)tok*1024;
  const float* wp = w + (size_t)n*1024;
  float s = 0;
#pragma unroll 4
  for (int j = 0; j < 16; ++j){
    int k = lane + j*64;
    s += hp[k] * wp[k];
  }
  s = wredsum(s);
  if (lane == 0) out[o] = s + bb[n] + centers[tok*3 + (n % 3)];
}

// =================================================================
extern "C" void kernel_launch(void* const* d_in, const int* in_sizes, int n_in,
                              void* d_out, int out_size, void* d_ws, size_t ws_size,
                              hipStream_t stream){
  const float* lh   = (const float*)d_in[0];
  const float* pc   = (const float*)d_in[1];
  const float* fpw  = (const float*)d_in[2];
  const float* fpb  = (const float*)d_in[3];
  const float* spw  = (const float*)d_in[4];
  const float* spb  = (const float*)d_in[5];
  const float* pos  = (const float*)d_in[6];
  const float* ln1w = (const float*)d_in[7];
  const float* ln1b = (const float*)d_in[8];
  const float* inw  = (const float*)d_in[9];
  const float* inb  = (const float*)d_in[10];
  const float* outw = (const float*)d_in[11];
  const float* outb = (const float*)d_in[12];
  const float* ln2w = (const float*)d_in[13];
  const float* ln2b = (const float*)d_in[14];
  const float* w1   = (const float*)d_in[15];
  const float* b1   = (const float*)d_in[16];
  const float* w2   = (const float*)d_in[17];
  const float* b2   = (const float*)d_in[18];
  const float* c1w  = (const float*)d_in[19];
  const float* c1b  = (const float*)d_in[20];
  const float* bng  = (const float*)d_in[21];
  const float* bnbt = (const float*)d_in[22];
  const float* bnm  = (const float*)d_in[23];
  const float* bnv  = (const float*)d_in[24];
  const float* c2w  = (const float*)d_in[25];
  const float* c2b  = (const float*)d_in[26];
  float* out = (float*)d_out;
  float* ws  = (float*)d_ws;

  float* Sbuf = ws;               // 524288  (32*128*128 attn scores/probs)
  float* part = Sbuf + 524288;    // 131072  (B*8*PH partial sums)
  float* mlh  = part + 131072;    // 16384   (B*PH mean)
  float* agg  = mlh  + 16384;     // 4096    (B*D)
  float* x    = agg  + 4096;      // 524288  (residual stream, B*G x D)
  float* xn   = x    + 524288;    // 524288  (LN output)
  float* qkv  = xn   + 524288;    // 1572864 (B*G x 3D)
  float* obuf = qkv  + 1572864;   // 524288  (attn out)
  float* hbuf = obuf + 524288;    // 2097152 (MLP hidden / c1 hidden)
  float* cent = hbuf + 2097152;   // 1536    (B*G*3 centers)

  fps_kernel<<<4, 1024, 0, stream>>>(pc, cent);
  partial_kernel<<<dim3(16,8,4), 256, 0, stream>>>(lh, part);
  combine_kernel<<<64, 256, 0, stream>>>(part, mlh);
  agg_kernel<<<1024, 256, 0, stream>>>(mlh, fpw, fpb, agg);
  sp_kernel<<<4096, 256, 0, stream>>>(agg, spw, spb, x);

  for (int l = 0; l < 4; ++l){
    ln_kernel<<<512, 256, 0, stream>>>(x, pos, ln1w + l*1024, ln1b + l*1024, xn);
    gemm64<0><<<dim3(48,8), 256, 0, stream>>>(xn, inw + (size_t)l*3072*1024, inb + l*3072,
                                              nullptr, qkv, 512, 3072, 1024,
                                              nullptr, nullptr, nullptr, nullptr);
    attn_qk<<<32, 256, 0, stream>>>(qkv, Sbuf);
    attn_sm<<<1024, 256, 0, stream>>>(Sbuf);
    attn_pv<<<32, 256, 0, stream>>>(Sbuf, qkv, obuf);
    gemm64<1><<<dim3(16,8), 256, 0, stream>>>(obuf, outw + (size_t)l*1024*1024, outb + l*1024,
                                              x, x, 512, 1024, 1024,
                                              nullptr, nullptr, nullptr, nullptr);
    ln_kernel<<<512, 256, 0, stream>>>(x, nullptr, ln2w + l*1024, ln2b + l*1024, xn);
    gemm64<2><<<dim3(64,8), 256, 0, stream>>>(xn, w1 + (size_t)l*4096*1024, b1 + l*4096,
                                              nullptr, hbuf, 512, 4096, 1024,
                                              nullptr, nullptr, nullptr, nullptr);
    gemm64<1><<<dim3(16,8), 256, 0, stream>>>(hbuf, w2 + (size_t)l*1024*4096, b2 + l*1024,
                                              x, x, 512, 1024, 4096,
                                              nullptr, nullptr, nullptr, nullptr);
  }

  gemm64<3><<<dim3(16,8), 256, 0, stream>>>(x, c1w, c1b, nullptr, hbuf, 512, 1024, 1024,
                                            bnm, bnv, bng, bnbt);
  c2_kernel<<<12288, 256, 0, stream>>>(hbuf, c2w, c2b, cent, out);
}

// Round 4
// 984.160 us; speedup vs baseline: 1.5048x; 1.4360x over previous
//
#include <hip/hip_runtime.h>
#include <hip/hip_bf16.h>
#include <math.h>

// Shapes (fixed): B=4, S=512, PH=4096, N=16384, D=1024, G=128, H=8, L=4, FF=4096, GS=32, HD=128

typedef __bf16 bf16x8_t __attribute__((ext_vector_type(8)));
typedef float  f32x4_t  __attribute__((ext_vector_type(4)));

__device__ __forceinline__ float wredsum(float v){
#pragma unroll
  for (int o = 32; o; o >>= 1) v += __shfl_down(v, o, 64);
  return v;  // valid in lane 0
}

__device__ __forceinline__ bf16x8_t pack8(float4 a, float4 b){
  bf16x8_t v;
  v[0]=(__bf16)a.x; v[1]=(__bf16)a.y; v[2]=(__bf16)a.z; v[3]=(__bf16)a.w;
  v[4]=(__bf16)b.x; v[5]=(__bf16)b.y; v[6]=(__bf16)b.z; v[7]=(__bf16)b.w;
  return v;
}

__device__ __forceinline__ void gload16(const void* g, void* l){
  __builtin_amdgcn_global_load_lds((const __attribute__((address_space(1))) unsigned int*)g,
                                   (__attribute__((address_space(3))) unsigned int*)l, 16, 0, 0);
}

// ---------------------------------------------------------------- FPS v3
// One block per batch, 1024 threads, 16 pts/thread in registers.
// u64 key = (dist_bits << 32) | (0xFFFFFFFF - idx): max key == (max dist, min idx).
// Wave shuffle-reduce on key; cross-wave via LDS atomicMax into per-iter slot
// (pre-zeroed, no reset). ONE barrier per iteration. Centroid coords re-fetched
// by uniform global load (L2). Distance arithmetic exact fp32 (matches np).
__global__ __launch_bounds__(1024) void fps_kernel(const float* __restrict__ pc,
                                                   float* __restrict__ centers){
  const int b = blockIdx.x;
  const int tid = threadIdx.x;
  const int lane = tid & 63;
  const float* base = pc + (size_t)b * 16384 * 3;
  float px[16], py[16], pz[16], dist[16];
  {
    union { float4 v4[12]; float f[48]; } u;
    const float4* src = (const float4*)(base + tid * 48);
#pragma unroll
    for (int q = 0; q < 12; ++q) u.v4[q] = src[q];
#pragma unroll
    for (int j = 0; j < 16; ++j){
      px[j] = u.f[j*3]; py[j] = u.f[j*3+1]; pz[j] = u.f[j*3+2];
      dist[j] = 1e10f;
    }
  }
  __shared__ unsigned long long keyslot[128];
  for (int i = tid; i < 128; i += 1024) keyslot[i] = 0ULL;
  __syncthreads();
  float cx = base[0], cy = base[1], cz = base[2];
  for (int t = 0; t < 128; ++t){
    if (tid == 0){
      centers[(b*128+t)*3+0] = cx;
      centers[(b*128+t)*3+1] = cy;
      centers[(b*128+t)*3+2] = cz;
    }
    if (t == 127) break;
    float bmax = -1.0f; int bidx = 0;
#pragma unroll
    for (int j = 0; j < 16; ++j){
      float dx = __fsub_rn(px[j], cx);
      float dy = __fsub_rn(py[j], cy);
      float dz = __fsub_rn(pz[j], cz);
      float d  = __fadd_rn(__fadd_rn(__fmul_rn(dx,dx), __fmul_rn(dy,dy)), __fmul_rn(dz,dz));
      float nd = fminf(dist[j], d);
      dist[j] = nd;
      if (nd > bmax){ bmax = nd; bidx = tid*16 + j; }
    }
    unsigned long long key = ((unsigned long long)__float_as_uint(bmax) << 32)
                           | (unsigned long long)(0xFFFFFFFFu - (unsigned)bidx);
#pragma unroll
    for (int o = 32; o; o >>= 1){
      unsigned long long ok = __shfl_down(key, o, 64);
      if (ok > key) key = ok;
    }
    if (lane == 0) atomicMax(&keyslot[t], key);
    __syncthreads();
    const unsigned long long gk = keyslot[t];
    const unsigned gidx = 0xFFFFFFFFu - (unsigned)(gk & 0xFFFFFFFFu);
    const float* cp = base + (size_t)gidx*3;
    cx = cp[0]; cy = cp[1]; cz = cp[2];
  }
}

// ------------------------------------------------- mean over S (2-stage)
__global__ __launch_bounds__(256) void partial_kernel(const float* __restrict__ lh,
                                                      float* __restrict__ part){
  const int ph = blockIdx.x*256 + threadIdx.x;
  const int sc = blockIdx.y, b = blockIdx.z;
  const float* p = lh + ((size_t)b*512 + sc*64)*4096 + ph;
  float s0=0,s1=0,s2=0,s3=0;
  for (int j = 0; j < 64; j += 4){
    s0 += p[(size_t)(j+0)*4096];
    s1 += p[(size_t)(j+1)*4096];
    s2 += p[(size_t)(j+2)*4096];
    s3 += p[(size_t)(j+3)*4096];
  }
  part[(size_t)(b*8+sc)*4096 + ph] = (s0+s1)+(s2+s3);
}

__global__ __launch_bounds__(256) void combine_kernel(const float* __restrict__ part,
                                                      float* __restrict__ mlh){
  const int i = blockIdx.x*256 + threadIdx.x;
  const int b = i >> 12, ph = i & 4095;
  float s = 0;
#pragma unroll
  for (int sc = 0; sc < 8; ++sc) s += part[(size_t)(b*8+sc)*4096 + ph];
  mlh[i] = s * (1.0f/512.0f);
}

// ------------------------------------------------- agg = mean_lh @ fp_w.T + fp_b
__global__ __launch_bounds__(256) void agg_kernel(const float* __restrict__ mlh,
                                                  const float* __restrict__ fpw,
                                                  const float* __restrict__ fpb,
                                                  float* __restrict__ agg){
  const int o = blockIdx.x*4 + (threadIdx.x>>6);
  const int lane = threadIdx.x & 63;
  const int b = o >> 10, d = o & 1023;
  const float* mp = mlh + b*4096;
  const float* wp = fpw + (size_t)d*4096;
  float s = 0;
#pragma unroll 4
  for (int j = 0; j < 64; ++j){
    int ph = lane + j*64;
    s += mp[ph] * wp[ph];
  }
  s = wredsum(s);
  if (lane == 0) agg[o] = s + fpb[d];
}

// ------------------------------------------------- x0 = agg @ sp_w.T + sp_b (537 MB, BW-bound)
__global__ __launch_bounds__(256) void sp_kernel(const float* __restrict__ agg,
                                                 const float* __restrict__ spw,
                                                 const float* __restrict__ spb,
                                                 float* __restrict__ x){
  __shared__ float ag[4*1024];
  for (int i = threadIdx.x; i < 4096; i += 256) ag[i] = agg[i];
  __syncthreads();
  const int wv = threadIdx.x >> 6, lane = threadIdx.x & 63;
  const int rbase = (blockIdx.x*4 + wv) * 8;
  for (int rr = 0; rr < 8; ++rr){
    const int row = rbase + rr;
    const float* wp = spw + (size_t)row*1024 + lane*4;
    const float4 w0 = *(const float4*)(wp      );
    const float4 w1 = *(const float4*)(wp + 256);
    const float4 w2 = *(const float4*)(wp + 512);
    const float4 w3 = *(const float4*)(wp + 768);
    float acc[4];
#pragma unroll
    for (int bb = 0; bb < 4; ++bb){
      const float* gp = &ag[bb*1024 + lane*4];
      const float4 g0 = *(const float4*)(gp      );
      const float4 g1 = *(const float4*)(gp + 256);
      const float4 g2 = *(const float4*)(gp + 512);
      const float4 g3 = *(const float4*)(gp + 768);
      acc[bb] = w0.x*g0.x + w0.y*g0.y + w0.z*g0.z + w0.w*g0.w
              + w1.x*g1.x + w1.y*g1.y + w1.z*g1.z + w1.w*g1.w
              + w2.x*g2.x + w2.y*g2.y + w2.z*g2.z + w2.w*g2.w
              + w3.x*g3.x + w3.y*g3.y + w3.z*g3.z + w3.w*g3.w;
    }
    float a0 = wredsum(acc[0]);
    float a1 = wredsum(acc[1]);
    float a2 = wredsum(acc[2]);
    float a3 = wredsum(acc[3]);
    if (lane == 0){
      const float bias = spb[row];
      x[(size_t)0*131072 + row] = a0 + bias;
      x[(size_t)1*131072 + row] = a1 + bias;
      x[(size_t)2*131072 + row] = a2 + bias;
      x[(size_t)3*131072 + row] = a3 + bias;
    }
  }
}

// ------------------------------------------------- weight fp32 -> bf16 (one layer's 4 mats)
__global__ __launch_bounds__(256) void wconv_layer(const float* __restrict__ inw,
                                                   const float* __restrict__ outw,
                                                   const float* __restrict__ w1,
                                                   const float* __restrict__ w2,
                                                   __bf16* __restrict__ wbf){
  const size_t TOT8 = 12582912/8;
  for (size_t t = (size_t)blockIdx.x*256 + threadIdx.x; t < TOT8; t += (size_t)gridDim.x*256){
    size_t i = t*8;
    const float* src;
    if (i < 3145728)       src = inw  + i;
    else if (i < 4194304)  src = outw + (i-3145728);
    else if (i < 8388608)  src = w1   + (i-4194304);
    else                   src = w2   + (i-8388608);
    float4 a = *(const float4*)src, bq = *(const float4*)(src+4);
    *(bf16x8_t*)(wbf + i) = pack8(a, bq);
  }
}

__global__ __launch_bounds__(256) void cvt_bf(const float* __restrict__ src,
                                              __bf16* __restrict__ dst, int n8){
  int t = blockIdx.x*256 + threadIdx.x;
  if (t >= n8) return;
  size_t i = (size_t)t*8;
  float4 a = *(const float4*)(src+i), bq = *(const float4*)(src+i+4);
  *(bf16x8_t*)(dst + i) = pack8(a, bq);
}

// ------------------------------------------------- LayerNorm (optionally + pos), bf16 out
__global__ __launch_bounds__(256) void ln_kernel(const float* __restrict__ x,
                                                 const float* __restrict__ pos,
                                                 const float* __restrict__ w,
                                                 const float* __restrict__ bb,
                                                 __bf16* __restrict__ out){
  const int tok = blockIdx.x, g = tok & 127, t = threadIdx.x;
  const int lane = t & 63, wv = t >> 6;
  const float* xr = x + (size_t)tok*1024;
  float v[4];
#pragma unroll
  for (int j = 0; j < 4; ++j){
    int d = t + j*256;
    float val = xr[d];
    if (pos) val += pos[g*1024 + d];
    v[j] = val;
  }
  __shared__ float r1[4], r2[4];
  float s = wredsum(v[0]+v[1]+v[2]+v[3]);
  if (lane == 0) r1[wv] = s;
  __syncthreads();
  const float mean = (r1[0]+r1[1]+r1[2]+r1[3]) * (1.0f/1024.0f);
  float sq = 0;
#pragma unroll
  for (int j = 0; j < 4; ++j){ float d0 = v[j]-mean; sq += d0*d0; }
  sq = wredsum(sq);
  if (lane == 0) r2[wv] = sq;
  __syncthreads();
  const float var = (r2[0]+r2[1]+r2[2]+r2[3]) * (1.0f/1024.0f);
  const float rs = rsqrtf(var + 1e-5f);
#pragma unroll
  for (int j = 0; j < 4; ++j){
    int d = t + j*256;
    out[(size_t)tok*1024 + d] = (__bf16)((v[j]-mean)*rs*w[d] + bb[d]);
  }
}

// ------------------------------------------------- bf16 MFMA GEMM, 128x128 tile (m97 recipe)
// C = A @ W.T (+bias/epilogue). A:[M][K] bf16, W:[N][K] bf16 (row stride K).
// Each 128-row x 32-col (64B) LDS tile = 512 x 16B chunks; chunk c covers
// row = c>>2, quarter q = c&3 at LDS element offset c*8 (linear, so the
// global_load_lds wave-uniform-base + lane*16B rule is satisfied).
// EPI: 0 = bias -> bf16 C;  2 = bias + exact GELU -> bf16 C;  4 = fp32 partial (split-K, no bias)
template<int EPI>
__global__ __launch_bounds__(256) void gemm128(
  const __bf16* __restrict__ A, const __bf16* __restrict__ W,
  const float* __restrict__ bias, void* __restrict__ Cv,
  int M, int N, int K, int kc)
{
  __shared__ __bf16 As[128*32];
  __shared__ __bf16 Ws[128*32];
  const int n0 = blockIdx.x*128, m0 = blockIdx.y*128, z = blockIdx.z;
  const int tid = threadIdx.x;
  const int lane = tid & 63, w = tid >> 6;
  const int wm = w >> 1, wn = w & 1;
  const int lr = lane & 15, g = lane >> 4;
  const int kbeg = z*kc, kend = kbeg + kc;
  f32x4_t acc[4][4] = {};
  for (int k0 = kbeg; k0 < kend; k0 += 32){
    __syncthreads();
#pragma unroll
    for (int i = 0; i < 2; ++i){
      const int c = tid + i*256;          // chunk 0..511: row=c>>2, quarter=c&3
      const int row = c >> 2, q = c & 3;
      gload16(A + (size_t)(m0+row)*K + k0 + q*8, &As[(size_t)c*8]);
      gload16(W + (size_t)(n0+row)*K + k0 + q*8, &Ws[(size_t)c*8]);
    }
    __syncthreads();
    bf16x8_t af[4], bf[4];
#pragma unroll
    for (int f = 0; f < 4; ++f){
      af[f] = *(bf16x8_t*)&As[(wm*64 + f*16 + lr)*32 + g*8];
      bf[f] = *(bf16x8_t*)&Ws[(wn*64 + f*16 + lr)*32 + g*8];
    }
#pragma unroll
    for (int i = 0; i < 4; ++i)
#pragma unroll
      for (int j = 0; j < 4; ++j)
        acc[i][j] = __builtin_amdgcn_mfma_f32_16x16x32_bf16(af[i], bf[j], acc[i][j], 0, 0, 0);
  }
  if (EPI == 4){
    float* C = (float*)Cv + (size_t)z*M*N;
#pragma unroll
    for (int i = 0; i < 4; ++i)
#pragma unroll
      for (int j = 0; j < 4; ++j)
#pragma unroll
        for (int r = 0; r < 4; ++r){
          const int row = m0 + wm*64 + i*16 + g*4 + r;
          const int col = n0 + wn*64 + j*16 + lr;
          C[(size_t)row*N + col] = acc[i][j][r];
        }
  } else {
    __bf16* C = (__bf16*)Cv;
#pragma unroll
    for (int i = 0; i < 4; ++i)
#pragma unroll
      for (int j = 0; j < 4; ++j)
#pragma unroll
        for (int r = 0; r < 4; ++r){
          const int row = m0 + wm*64 + i*16 + g*4 + r;
          const int col = n0 + wn*64 + j*16 + lr;
          float v = acc[i][j][r] + bias[col];
          if (EPI == 2) v = v * 0.5f * (1.0f + erff(v * 0.70710678118654752440f));
          C[(size_t)row*N + col] = (__bf16)v;
        }
  }
}

// ------------------------------------------------- split-K combine: x += sum(parts)+bias (+bf copy)
__global__ __launch_bounds__(256) void comb_res(const float* __restrict__ parts, int nsplit,
                                                const float* __restrict__ bias,
                                                float* __restrict__ x,
                                                __bf16* __restrict__ xb){
  const int i = blockIdx.x*256 + threadIdx.x;   // 0..524287
  float s = 0;
  for (int z = 0; z < nsplit; ++z) s += parts[(size_t)z*524288 + i];
  const float v = x[i] + s + bias[i & 1023];
  x[i] = v;
  if (xb) xb[i] = (__bf16)v;
}

// ------------------------------------------------- split-K combine: BN(eval)+ReLU -> fp32
__global__ __launch_bounds__(256) void comb_bn(const float* __restrict__ parts, int nsplit,
                                               const float* __restrict__ bias,
                                               const float* __restrict__ bnm,
                                               const float* __restrict__ bnv,
                                               const float* __restrict__ bng,
                                               const float* __restrict__ bnb,
                                               float* __restrict__ out){
  const int i = blockIdx.x*256 + threadIdx.x;
  const int c = i & 1023;
  float s = 0;
  for (int z = 0; z < nsplit; ++z) s += parts[(size_t)z*524288 + i];
  float v = s + bias[c];
  v = (v - bnm[c]) * rsqrtf(bnv[c] + 1e-5f) * bng[c] + bnb[c];
  out[i] = fmaxf(v, 0.0f);
}

// ------------------------------------------------- attention: S = scale * Q @ K.T (bf16 qkv)
__global__ __launch_bounds__(256) void attn_qk(const __bf16* __restrict__ qkv,
                                               float* __restrict__ S){
  const int bh = blockIdx.x, b = bh >> 3, h = bh & 7;
  const int tid = threadIdx.x, w = tid>>6, lane = tid&63;
  const int wm = w>>1, wn = w&1;
  const int lr = lane&15, g = lane>>4;
  const __bf16* qbase = qkv + (size_t)(b*128)*3072 + h*128;
  const __bf16* kbase = qbase + 1024;
  f32x4_t acc[4][4] = {};
#pragma unroll
  for (int ks = 0; ks < 4; ++ks){
    bf16x8_t aq[4], bk[4];
#pragma unroll
    for (int f = 0; f < 4; ++f){
      aq[f] = *(const bf16x8_t*)(qbase + (size_t)(wm*64 + f*16 + lr)*3072 + ks*32 + g*8);
      bk[f] = *(const bf16x8_t*)(kbase + (size_t)(wn*64 + f*16 + lr)*3072 + ks*32 + g*8);
    }
#pragma unroll
    for (int i = 0; i < 4; ++i)
#pragma unroll
      for (int j = 0; j < 4; ++j)
        acc[i][j] = __builtin_amdgcn_mfma_f32_16x16x32_bf16(aq[i], bk[j], acc[i][j], 0, 0, 0);
  }
  const float scale = 0.088388347648318447f;  // 1/sqrt(128)
  float* sb = S + (size_t)bh*16384;
#pragma unroll
  for (int i = 0; i < 4; ++i)
#pragma unroll
    for (int j = 0; j < 4; ++j)
#pragma unroll
      for (int r = 0; r < 4; ++r){
        const int row = wm*64 + i*16 + g*4 + r;
        const int col = wn*64 + j*16 + lr;
        sb[row*128 + col] = acc[i][j][r] * scale;
      }
}

// ------------------------------------------------- softmax rows of S (in place), one wave/row
__global__ __launch_bounds__(256) void attn_sm(float* __restrict__ S){
  const int row = blockIdx.x*4 + (threadIdx.x>>6);
  const int lane = threadIdx.x & 63;
  float* p = S + (size_t)row*128;
  float v0 = p[lane], v1 = p[lane+64];
  float m = fmaxf(v0, v1);
#pragma unroll
  for (int o = 1; o < 64; o <<= 1) m = fmaxf(m, __shfl_xor(m, o, 64));
  float e0 = expf(v0 - m), e1 = expf(v1 - m);
  float s = e0 + e1;
#pragma unroll
  for (int o = 1; o < 64; o <<= 1) s += __shfl_xor(s, o, 64);
  const float inv = 1.0f / s;
  p[lane] = e0*inv; p[lane+64] = e1*inv;
}

// ------------------------------------------------- O = P @ V (V^T staged in swizzled LDS), bf16 out
__global__ __launch_bounds__(256) void attn_pv(const float* __restrict__ P,
                                               const __bf16* __restrict__ qkv,
                                               __bf16* __restrict__ O){
  const int bh = blockIdx.x, b = bh>>3, h = bh&7;
  const int tid = threadIdx.x, w = tid>>6, lane = tid&63;
  const int wm = w>>1, wn = w&1, lr = lane&15, g = lane>>4;
  __shared__ __bf16 vt[128*128];
  {
    const int n = tid >> 1, kh = tid & 1;
    const __bf16* vbase = qkv + (size_t)(b*128)*3072 + 2048 + h*128 + n;
#pragma unroll
    for (int jb = 0; jb < 8; ++jb){
      bf16x8_t pk;
#pragma unroll
      for (int e = 0; e < 8; ++e){
        int k = kh*64 + jb*8 + e;
        pk[e] = vbase[(size_t)k*3072];
      }
      int cb = kh*8 + jb;
      *(bf16x8_t*)&vt[n*128 + ((cb ^ (n&7)) * 8)] = pk;
    }
  }
  __syncthreads();
  const float* pb = P + (size_t)bh*16384;
  f32x4_t acc[4][4] = {};
#pragma unroll
  for (int ks = 0; ks < 4; ++ks){
    bf16x8_t ap[4], bv[4];
#pragma unroll
    for (int f = 0; f < 4; ++f){
      const float* p = pb + (size_t)(wm*64 + f*16 + lr)*128 + ks*32 + g*8;
      ap[f] = pack8(*(const float4*)p, *(const float4*)(p+4));
      const int rowv = wn*64 + f*16 + lr;
      const int cb = ks*4 + g;
      bv[f] = *(bf16x8_t*)&vt[rowv*128 + ((cb ^ (rowv&7)) * 8)];
    }
#pragma unroll
    for (int i = 0; i < 4; ++i)
#pragma unroll
      for (int j = 0; j < 4; ++j)
        acc[i][j] = __builtin_amdgcn_mfma_f32_16x16x32_bf16(ap[i], bv[j], acc[i][j], 0, 0, 0);
  }
#pragma unroll
  for (int i = 0; i < 4; ++i)
#pragma unroll
    for (int j = 0; j < 4; ++j)
#pragma unroll
      for (int r = 0; r < 4; ++r){
        const int row = wm*64 + i*16 + g*4 + r;
        const int col = wn*64 + j*16 + lr;
        O[(size_t)(b*128+row)*1024 + h*128 + col] = (__bf16)acc[i][j][r];
      }
}

// ------------------------------------------------- final head: out = h @ c2_w.T + c2_b + centers
__global__ __launch_bounds__(256) void c2_kernel(const float* __restrict__ hb,
                                                 const float* __restrict__ w,
                                                 const float* __restrict__ bb,
                                                 const float* __restrict__ centers,
                                                 float* __restrict__ out){
  const int o = blockIdx.x*4 + (threadIdx.x>>6);
  const int lane = threadIdx.x & 63;
  const int tok = o / 96, n = o % 96;
  const float* hp = hb + (size_t)tok*1024;
  const float* wp = w + (size_t)n*1024;
  float s = 0;
#pragma unroll 4
  for (int j = 0; j < 16; ++j){
    int k = lane + j*64;
    s += hp[k] * wp[k];
  }
  s = wredsum(s);
  if (lane == 0) out[o] = s + bb[n] + centers[tok*3 + (n % 3)];
}

// =================================================================
extern "C" void kernel_launch(void* const* d_in, const int* in_sizes, int n_in,
                              void* d_out, int out_size, void* d_ws, size_t ws_size,
                              hipStream_t stream){
  const float* lh   = (const float*)d_in[0];
  const float* pc   = (const float*)d_in[1];
  const float* fpw  = (const float*)d_in[2];
  const float* fpb  = (const float*)d_in[3];
  const float* spw  = (const float*)d_in[4];
  const float* spb  = (const float*)d_in[5];
  const float* pos  = (const float*)d_in[6];
  const float* ln1w = (const float*)d_in[7];
  const float* ln1b = (const float*)d_in[8];
  const float* inw  = (const float*)d_in[9];
  const float* inb  = (const float*)d_in[10];
  const float* outw = (const float*)d_in[11];
  const float* outb = (const float*)d_in[12];
  const float* ln2w = (const float*)d_in[13];
  const float* ln2b = (const float*)d_in[14];
  const float* w1   = (const float*)d_in[15];
  const float* b1   = (const float*)d_in[16];
  const float* w2   = (const float*)d_in[17];
  const float* b2   = (const float*)d_in[18];
  const float* c1w  = (const float*)d_in[19];
  const float* c1b  = (const float*)d_in[20];
  const float* bng  = (const float*)d_in[21];
  const float* bnbt = (const float*)d_in[22];
  const float* bnm  = (const float*)d_in[23];
  const float* bnv  = (const float*)d_in[24];
  const float* c2w  = (const float*)d_in[25];
  const float* c2b  = (const float*)d_in[26];
  float* out = (float*)d_out;

  // ---- workspace layout (fp32 region then bf16 region; all 16B aligned) ----
  float* f = (float*)d_ws;
  float* parts = f;              f += 4*524288;   // split-K partials (max 4)
  float* Sbuf  = f;              f += 524288;     // attn scores/probs fp32
  float* part  = f;              f += 131072;
  float* mlh   = f;              f += 16384;
  float* agg   = f;              f += 4096;
  float* x     = f;              f += 524288;     // residual stream fp32
  float* hc1   = f;              f += 524288;     // c1 output (BN+ReLU) fp32
  float* cent  = f;              f += 1536 + 512; // centers (+pad to 16B multiple)
  __bf16* bf = (__bf16*)f;
  __bf16* xn   = bf;             bf += 524288;    // LN out
  __bf16* qkv  = bf;             bf += 1572864;
  __bf16* obuf = bf;             bf += 524288;
  __bf16* hbf  = bf;             bf += 2097152;   // MLP hidden (GELU) bf16
  __bf16* xbf  = bf;             bf += 524288;    // bf16 copy of final x
  __bf16* wbf  = bf;             bf += 12582912;  // current layer's weights bf16
  __bf16* c1bf = bf;             bf += 1048576;

  fps_kernel<<<4, 1024, 0, stream>>>(pc, cent);
  partial_kernel<<<dim3(16,8,4), 256, 0, stream>>>(lh, part);
  combine_kernel<<<64, 256, 0, stream>>>(part, mlh);
  agg_kernel<<<1024, 256, 0, stream>>>(mlh, fpw, fpb, agg);
  sp_kernel<<<4096, 256, 0, stream>>>(agg, spw, spb, x);

  for (int l = 0; l < 4; ++l){
    wconv_layer<<<2048, 256, 0, stream>>>(inw + (size_t)l*3145728, outw + (size_t)l*1048576,
                                          w1 + (size_t)l*4194304, w2 + (size_t)l*4194304, wbf);
    ln_kernel<<<512, 256, 0, stream>>>(x, pos, ln1w + l*1024, ln1b + l*1024, xn);
    gemm128<0><<<dim3(24,4,1), 256, 0, stream>>>(xn, wbf, inb + l*3072, qkv,
                                                 512, 3072, 1024, 1024);
    attn_qk<<<32, 256, 0, stream>>>(qkv, Sbuf);
    attn_sm<<<1024, 256, 0, stream>>>(Sbuf);
    attn_pv<<<32, 256, 0, stream>>>(Sbuf, qkv, obuf);
    gemm128<4><<<dim3(8,4,2), 256, 0, stream>>>(obuf, wbf + 3145728, nullptr, parts,
                                                512, 1024, 1024, 512);
    comb_res<<<2048, 256, 0, stream>>>(parts, 2, outb + l*1024, x, nullptr);
    ln_kernel<<<512, 256, 0, stream>>>(x, nullptr, ln2w + l*1024, ln2b + l*1024, xn);
    gemm128<2><<<dim3(32,4,1), 256, 0, stream>>>(xn, wbf + 4194304, b1 + l*4096, hbf,
                                                 512, 4096, 1024, 1024);
    gemm128<4><<<dim3(8,4,4), 256, 0, stream>>>(hbf, wbf + 8388608, nullptr, parts,
                                                512, 1024, 4096, 1024);
    comb_res<<<2048, 256, 0, stream>>>(parts, 4, b2 + l*1024, x, (l==3) ? xbf : nullptr);
  }

  cvt_bf<<<512, 256, 0, stream>>>(c1w, c1bf, 131072);
  gemm128<4><<<dim3(8,4,2), 256, 0, stream>>>(xbf, c1bf, nullptr, parts,
                                              512, 1024, 1024, 512);
  comb_bn<<<2048, 256, 0, stream>>>(parts, 2, c1b, bnm, bnv, bng, bnbt, hc1);
  c2_kernel<<<12288, 256, 0, stream>>>(hc1, c2w, c2b, cent, out);
}

// Round 5
// 800.860 us; speedup vs baseline: 1.8493x; 1.2289x over previous
//
#include <hip/hip_runtime.h>
#include <hip/hip_bf16.h>
#include <math.h>

// Shapes (fixed): B=4, S=512, PH=4096, N=16384, D=1024, G=128, H=8, L=4, FF=4096, GS=32, HD=128

typedef __bf16 bf16x8_t __attribute__((ext_vector_type(8)));
typedef float  f32x4_t  __attribute__((ext_vector_type(4)));

__device__ __forceinline__ float wredsum(float v){
#pragma unroll
  for (int o = 32; o; o >>= 1) v += __shfl_down(v, o, 64);
  return v;  // valid in lane 0
}

__device__ __forceinline__ bf16x8_t pack8(float4 a, float4 b){
  bf16x8_t v;
  v[0]=(__bf16)a.x; v[1]=(__bf16)a.y; v[2]=(__bf16)a.z; v[3]=(__bf16)a.w;
  v[4]=(__bf16)b.x; v[5]=(__bf16)b.y; v[6]=(__bf16)b.z; v[7]=(__bf16)b.w;
  return v;
}

__device__ __forceinline__ void gload16(const void* g, void* l){
  __builtin_amdgcn_global_load_lds((const __attribute__((address_space(1))) unsigned int*)g,
                                   (__attribute__((address_space(3))) unsigned int*)l, 16, 0, 0);
}

// ---------------------------------------------------------------- fused front-end
// blocks 0..3: FPS (per batch, latency-bound, ~135us on 4 CUs)
// blocks 4..1027: sp GEMV (537 MB, BW-bound)
// blocks 1028..7299: weight fp32->bf16 conversion (308 MB, BW-bound)
// The BW work streams on 252 CUs while FPS runs; total ~= max(fps, BW).
__global__ __launch_bounds__(1024) void fused_front(
  const float* __restrict__ pc, float* __restrict__ centers,
  const float* __restrict__ agg, const float* __restrict__ spw,
  const float* __restrict__ spb, float* __restrict__ x,
  const float* __restrict__ inw, const float* __restrict__ outw,
  const float* __restrict__ w1, const float* __restrict__ w2,
  const float* __restrict__ c1w, __bf16* __restrict__ wbf)
{
  const int bid = blockIdx.x;
  const int tid = threadIdx.x;
  if (bid < 4){
    // ---------------- FPS v3 (validated R4) ----------------
    const int b = bid;
    const int lane = tid & 63;
    const float* base = pc + (size_t)b * 16384 * 3;
    float px[16], py[16], pz[16], dist[16];
    {
      union { float4 v4[12]; float f[48]; } u;
      const float4* src = (const float4*)(base + tid * 48);
#pragma unroll
      for (int q = 0; q < 12; ++q) u.v4[q] = src[q];
#pragma unroll
      for (int j = 0; j < 16; ++j){
        px[j] = u.f[j*3]; py[j] = u.f[j*3+1]; pz[j] = u.f[j*3+2];
        dist[j] = 1e10f;
      }
    }
    __shared__ unsigned long long keyslot[128];
    for (int i = tid; i < 128; i += 1024) keyslot[i] = 0ULL;
    __syncthreads();
    float cx = base[0], cy = base[1], cz = base[2];
    for (int t = 0; t < 128; ++t){
      if (tid == 0){
        centers[(b*128+t)*3+0] = cx;
        centers[(b*128+t)*3+1] = cy;
        centers[(b*128+t)*3+2] = cz;
      }
      if (t == 127) break;
      float bmax = -1.0f; int bidx = 0;
#pragma unroll
      for (int j = 0; j < 16; ++j){
        float dx = __fsub_rn(px[j], cx);
        float dy = __fsub_rn(py[j], cy);
        float dz = __fsub_rn(pz[j], cz);
        float d  = __fadd_rn(__fadd_rn(__fmul_rn(dx,dx), __fmul_rn(dy,dy)), __fmul_rn(dz,dz));
        float nd = fminf(dist[j], d);
        dist[j] = nd;
        if (nd > bmax){ bmax = nd; bidx = tid*16 + j; }
      }
      unsigned long long key = ((unsigned long long)__float_as_uint(bmax) << 32)
                             | (unsigned long long)(0xFFFFFFFFu - (unsigned)bidx);
#pragma unroll
      for (int o = 32; o; o >>= 1){
        unsigned long long ok = __shfl_down(key, o, 64);
        if (ok > key) key = ok;
      }
      if (lane == 0) atomicMax(&keyslot[t], key);
      __syncthreads();
      const unsigned long long gk = keyslot[t];
      const unsigned gidx = 0xFFFFFFFFu - (unsigned)(gk & 0xFFFFFFFFu);
      const float* cp = base + (size_t)gidx*3;
      cx = cp[0]; cy = cp[1]; cz = cp[2];
    }
  } else if (bid < 1028){
    // ---------------- sp: x0 = agg @ sp_w.T + sp_b ----------------
    __shared__ float ag[4096];
    for (int i = tid; i < 4096; i += 1024) ag[i] = agg[i];
    __syncthreads();
    const int wv = tid >> 6, lane = tid & 63;
    const int rbase = ((bid - 4)*16 + wv)*8;
    for (int rr = 0; rr < 8; ++rr){
      const int row = rbase + rr;
      const float* wp = spw + (size_t)row*1024 + lane*4;
      const float4 w0 = *(const float4*)(wp      );
      const float4 wq1 = *(const float4*)(wp + 256);
      const float4 wq2 = *(const float4*)(wp + 512);
      const float4 wq3 = *(const float4*)(wp + 768);
      float acc[4];
#pragma unroll
      for (int bb = 0; bb < 4; ++bb){
        const float* gp = &ag[bb*1024 + lane*4];
        const float4 g0 = *(const float4*)(gp      );
        const float4 g1 = *(const float4*)(gp + 256);
        const float4 g2 = *(const float4*)(gp + 512);
        const float4 g3 = *(const float4*)(gp + 768);
        acc[bb] = w0.x*g0.x + w0.y*g0.y + w0.z*g0.z + w0.w*g0.w
                + wq1.x*g1.x + wq1.y*g1.y + wq1.z*g1.z + wq1.w*g1.w
                + wq2.x*g2.x + wq2.y*g2.y + wq2.z*g2.z + wq2.w*g2.w
                + wq3.x*g3.x + wq3.y*g3.y + wq3.z*g3.z + wq3.w*g3.w;
      }
      float a0 = wredsum(acc[0]);
      float a1 = wredsum(acc[1]);
      float a2 = wredsum(acc[2]);
      float a3 = wredsum(acc[3]);
      if (lane == 0){
        const float bias = spb[row];
        x[(size_t)0*131072 + row] = a0 + bias;
        x[(size_t)1*131072 + row] = a1 + bias;
        x[(size_t)2*131072 + row] = a2 + bias;
        x[(size_t)3*131072 + row] = a3 + bias;
      }
    }
  } else {
    // ---------------- weight fp32 -> bf16 (all 4 layers + c1) ----------------
    // layout per layer l at wbf + l*12582912: [inw 3145728][outw 1048576][w1 4194304][w2 4194304]
    // c1 at wbf + 50331648 (1048576). Total 51380224 elems = 6422528 chunks of 8.
    const size_t t = (size_t)(bid - 1028)*1024 + tid;   // exactly 6272*1024 chunks
    const size_t i = t*8;
    const float* src;
    if (i < 50331648){
      const size_t l = i / 12582912, r = i - l*12582912;
      if (r < 3145728)       src = inw  + l*3145728 + r;
      else if (r < 4194304)  src = outw + l*1048576 + (r-3145728);
      else if (r < 8388608)  src = w1   + l*4194304 + (r-4194304);
      else                   src = w2   + l*4194304 + (r-8388608);
    } else src = c1w + (i - 50331648);
    float4 a = *(const float4*)src, bq = *(const float4*)(src+4);
    *(bf16x8_t*)(wbf + i) = pack8(a, bq);
  }
}

// ------------------------------------------------- mean over S (2-stage)
__global__ __launch_bounds__(256) void partial_kernel(const float* __restrict__ lh,
                                                      float* __restrict__ part){
  const int ph = blockIdx.x*256 + threadIdx.x;
  const int sc = blockIdx.y, b = blockIdx.z;
  const float* p = lh + ((size_t)b*512 + sc*64)*4096 + ph;
  float s0=0,s1=0,s2=0,s3=0;
  for (int j = 0; j < 64; j += 4){
    s0 += p[(size_t)(j+0)*4096];
    s1 += p[(size_t)(j+1)*4096];
    s2 += p[(size_t)(j+2)*4096];
    s3 += p[(size_t)(j+3)*4096];
  }
  part[(size_t)(b*8+sc)*4096 + ph] = (s0+s1)+(s2+s3);
}

__global__ __launch_bounds__(256) void combine_kernel(const float* __restrict__ part,
                                                      float* __restrict__ mlh){
  const int i = blockIdx.x*256 + threadIdx.x;
  const int b = i >> 12, ph = i & 4095;
  float s = 0;
#pragma unroll
  for (int sc = 0; sc < 8; ++sc) s += part[(size_t)(b*8+sc)*4096 + ph];
  mlh[i] = s * (1.0f/512.0f);
}

// ------------------------------------------------- agg = mean_lh @ fp_w.T + fp_b
__global__ __launch_bounds__(256) void agg_kernel(const float* __restrict__ mlh,
                                                  const float* __restrict__ fpw,
                                                  const float* __restrict__ fpb,
                                                  float* __restrict__ agg){
  const int o = blockIdx.x*4 + (threadIdx.x>>6);
  const int lane = threadIdx.x & 63;
  const int b = o >> 10, d = o & 1023;
  const float* mp = mlh + b*4096;
  const float* wp = fpw + (size_t)d*4096;
  float s = 0;
#pragma unroll 4
  for (int j = 0; j < 64; ++j){
    int ph = lane + j*64;
    s += mp[ph] * wp[ph];
  }
  s = wredsum(s);
  if (lane == 0) agg[o] = s + fpb[d];
}

// ------------------------------------------------- LayerNorm (x + pos), bf16 out (layer-0 entry)
__global__ __launch_bounds__(256) void ln_kernel(const float* __restrict__ x,
                                                 const float* __restrict__ pos,
                                                 const float* __restrict__ w,
                                                 const float* __restrict__ bb,
                                                 __bf16* __restrict__ out){
  const int tok = blockIdx.x, g = tok & 127, t = threadIdx.x;
  const int lane = t & 63, wv = t >> 6;
  const float* xr = x + (size_t)tok*1024;
  float v[4];
#pragma unroll
  for (int j = 0; j < 4; ++j){
    int d = t + j*256;
    float val = xr[d];
    if (pos) val += pos[g*1024 + d];
    v[j] = val;
  }
  __shared__ float r1[4], r2[4];
  float s = wredsum(v[0]+v[1]+v[2]+v[3]);
  if (lane == 0) r1[wv] = s;
  __syncthreads();
  const float mean = (r1[0]+r1[1]+r1[2]+r1[3]) * (1.0f/1024.0f);
  float sq = 0;
#pragma unroll
  for (int j = 0; j < 4; ++j){ float d0 = v[j]-mean; sq += d0*d0; }
  sq = wredsum(sq);
  if (lane == 0) r2[wv] = sq;
  __syncthreads();
  const float var = (r2[0]+r2[1]+r2[2]+r2[3]) * (1.0f/1024.0f);
  const float rs = rsqrtf(var + 1e-5f);
#pragma unroll
  for (int j = 0; j < 4; ++j){
    int d = t + j*256;
    out[(size_t)tok*1024 + d] = (__bf16)((v[j]-mean)*rs*w[d] + bb[d]);
  }
}

// ------------------------------------------------- bf16 MFMA split-K GEMM, 128x128 tile
// parts[z] = A[:, z*kc:(z+1)*kc] @ W[:, z*kc:(z+1)*kc].T   (fp32 partials)
__global__ __launch_bounds__(256) void gemm_sk(
  const __bf16* __restrict__ A, const __bf16* __restrict__ W,
  float* __restrict__ parts, int M, int N, int K, int kc)
{
  __shared__ __bf16 As[128*32];
  __shared__ __bf16 Ws[128*32];
  const int n0 = blockIdx.x*128, m0 = blockIdx.y*128, z = blockIdx.z;
  const int tid = threadIdx.x;
  const int lane = tid & 63, w = tid >> 6;
  const int wm = w >> 1, wn = w & 1;
  const int lr = lane & 15, g = lane >> 4;
  const int kbeg = z*kc, kend = kbeg + kc;
  f32x4_t acc[4][4] = {};
  for (int k0 = kbeg; k0 < kend; k0 += 32){
    __syncthreads();
#pragma unroll
    for (int i = 0; i < 2; ++i){
      const int c = tid + i*256;          // chunk 0..511: row=c>>2, quarter=c&3
      const int row = c >> 2, q = c & 3;
      gload16(A + (size_t)(m0+row)*K + k0 + q*8, &As[(size_t)c*8]);
      gload16(W + (size_t)(n0+row)*K + k0 + q*8, &Ws[(size_t)c*8]);
    }
    __syncthreads();
    bf16x8_t af[4], bf[4];
#pragma unroll
    for (int f = 0; f < 4; ++f){
      af[f] = *(bf16x8_t*)&As[(wm*64 + f*16 + lr)*32 + g*8];
      bf[f] = *(bf16x8_t*)&Ws[(wn*64 + f*16 + lr)*32 + g*8];
    }
#pragma unroll
    for (int i = 0; i < 4; ++i)
#pragma unroll
      for (int j = 0; j < 4; ++j)
        acc[i][j] = __builtin_amdgcn_mfma_f32_16x16x32_bf16(af[i], bf[j], acc[i][j], 0, 0, 0);
  }
  float* C = parts + (size_t)z*M*N;
#pragma unroll
  for (int i = 0; i < 4; ++i)
#pragma unroll
    for (int j = 0; j < 4; ++j)
#pragma unroll
      for (int r = 0; r < 4; ++r){
        const int row = m0 + wm*64 + i*16 + g*4 + r;
        const int col = n0 + wn*64 + j*16 + lr;
        C[(size_t)row*N + col] = acc[i][j][r];
      }
}

// ------------------------------------------------- combines
__global__ __launch_bounds__(256) void comb_qkv(const float* __restrict__ parts,
                                                const float* __restrict__ bias,
                                                __bf16* __restrict__ out){
  const int i = blockIdx.x*256 + threadIdx.x;   // < 1572864
  const int col = i % 3072;
  out[i] = (__bf16)(parts[i] + parts[1572864 + i] + bias[col]);
}

__global__ __launch_bounds__(256) void comb_gelu(const float* __restrict__ parts,
                                                 const float* __restrict__ bias,
                                                 __bf16* __restrict__ out){
  const int i = blockIdx.x*256 + threadIdx.x;   // < 2097152
  const int col = i & 4095;
  float v = parts[i] + parts[2097152 + i] + bias[col];
  v = v * 0.5f * (1.0f + erff(v * 0.70710678118654752440f));
  out[i] = (__bf16)v;
}

// residual add (+bias, nsplit fp32 partials) into x, then optional LayerNorm -> bf16 xn.
// MODE 0: LN; MODE 1: LN with pos added to LN input; MODE 2: no LN, emit bf16 copy of x.
template<int MODE>
__global__ __launch_bounds__(256) void comb_res_ln(const float* __restrict__ parts, int nsplit,
                                                   const float* __restrict__ bias,
                                                   const float* __restrict__ pos,
                                                   const float* __restrict__ lw,
                                                   const float* __restrict__ lb,
                                                   float* __restrict__ x,
                                                   __bf16* __restrict__ xn){
  const int tok = blockIdx.x, gi = tok & 127, t = threadIdx.x;
  const int lane = t & 63, wv = t >> 6;
  float v[4];
#pragma unroll
  for (int j = 0; j < 4; ++j){
    const int d = t + j*256;
    const size_t idx = (size_t)tok*1024 + d;
    float s = 0;
    for (int z = 0; z < nsplit; ++z) s += parts[(size_t)z*524288 + idx];
    float val = x[idx] + s + bias[d];
    x[idx] = val;
    v[j] = val;
  }
  if (MODE == 2){
#pragma unroll
    for (int j = 0; j < 4; ++j){
      const int d = t + j*256;
      xn[(size_t)tok*1024 + d] = (__bf16)v[j];
    }
    return;
  }
  float u[4];
#pragma unroll
  for (int j = 0; j < 4; ++j){
    const int d = t + j*256;
    u[j] = v[j] + (MODE == 1 ? pos[gi*1024 + d] : 0.0f);
  }
  __shared__ float r1[4], r2[4];
  float s1 = wredsum(u[0]+u[1]+u[2]+u[3]);
  if (lane == 0) r1[wv] = s1;
  __syncthreads();
  const float mean = (r1[0]+r1[1]+r1[2]+r1[3]) * (1.0f/1024.0f);
  float sq = 0;
#pragma unroll
  for (int j = 0; j < 4; ++j){ float d0 = u[j]-mean; sq += d0*d0; }
  sq = wredsum(sq);
  if (lane == 0) r2[wv] = sq;
  __syncthreads();
  const float var = (r2[0]+r2[1]+r2[2]+r2[3]) * (1.0f/1024.0f);
  const float rs = rsqrtf(var + 1e-5f);
#pragma unroll
  for (int j = 0; j < 4; ++j){
    const int d = t + j*256;
    xn[(size_t)tok*1024 + d] = (__bf16)((u[j]-mean)*rs*lw[d] + lb[d]);
  }
}

__global__ __launch_bounds__(256) void comb_bn(const float* __restrict__ parts, int nsplit,
                                               const float* __restrict__ bias,
                                               const float* __restrict__ bnm,
                                               const float* __restrict__ bnv,
                                               const float* __restrict__ bng,
                                               const float* __restrict__ bnb,
                                               float* __restrict__ out){
  const int i = blockIdx.x*256 + threadIdx.x;
  const int c = i & 1023;
  float s = 0;
  for (int z = 0; z < nsplit; ++z) s += parts[(size_t)z*524288 + i];
  float v = s + bias[c];
  v = (v - bnm[c]) * rsqrtf(bnv[c] + 1e-5f) * bng[c] + bnb[c];
  out[i] = fmaxf(v, 0.0f);
}

// ------------------------------------------------- fused attention: one block per (b,h)
// wave w owns Q rows [w*32, w*32+32). QK^T from global, in-register softmax
// (16-lane-group shfl_xor), P -> swizzled LDS, PV with V^T swizzled LDS.
__global__ __launch_bounds__(256) void attn_fused(const __bf16* __restrict__ qkv,
                                                  __bf16* __restrict__ O){
  const int bh = blockIdx.x, b = bh>>3, h = bh&7;
  const int tid = threadIdx.x, w = tid>>6, lane = tid&63;
  const int lr = lane&15, g = lane>>4;
  __shared__ __bf16 vt[128*128];    // V^T, swizzled (validated layout)
  __shared__ __bf16 pl[4*4096];     // per-wave P (32x128), swizzled
  {
    const int n = tid >> 1, kh = tid & 1;
    const __bf16* vbase = qkv + (size_t)(b*128)*3072 + 2048 + h*128 + n;
#pragma unroll
    for (int jb = 0; jb < 8; ++jb){
      bf16x8_t pk;
#pragma unroll
      for (int e = 0; e < 8; ++e) pk[e] = vbase[(size_t)(kh*64 + jb*8 + e)*3072];
      const int cb = kh*8 + jb;
      *(bf16x8_t*)&vt[n*128 + ((cb ^ (n&7)) * 8)] = pk;
    }
  }
  // QK^T: acc[i][j] covers rows w*32+i*16+g*4+r, cols j*16+lr
  const __bf16* qbase = qkv + (size_t)(b*128)*3072 + h*128;
  const __bf16* kbase = qbase + 1024;
  f32x4_t acc[2][8] = {};
#pragma unroll
  for (int ks = 0; ks < 4; ++ks){
    bf16x8_t aq[2], bk[8];
#pragma unroll
    for (int i = 0; i < 2; ++i)
      aq[i] = *(const bf16x8_t*)(qbase + (size_t)(w*32 + i*16 + lr)*3072 + ks*32 + g*8);
#pragma unroll
    for (int j = 0; j < 8; ++j)
      bk[j] = *(const bf16x8_t*)(kbase + (size_t)(j*16 + lr)*3072 + ks*32 + g*8);
#pragma unroll
    for (int i = 0; i < 2; ++i)
#pragma unroll
      for (int j = 0; j < 8; ++j)
        acc[i][j] = __builtin_amdgcn_mfma_f32_16x16x32_bf16(aq[i], bk[j], acc[i][j], 0, 0, 0);
  }
  __syncthreads();   // vt staging complete before PV reads
  const float scale = 0.088388347648318447f;  // 1/sqrt(128)
  // softmax per row (row = i*16 + g*4 + r local); 128 cols = 8 j-frags x 16 lanes (lr)
#pragma unroll
  for (int i = 0; i < 2; ++i)
#pragma unroll
    for (int r = 0; r < 4; ++r){
      const int row = i*16 + g*4 + r;
      float sv[8];
      float mx = -1e30f;
#pragma unroll
      for (int j = 0; j < 8; ++j){ sv[j] = acc[i][j][r]*scale; mx = fmaxf(mx, sv[j]); }
#pragma unroll
      for (int o = 1; o < 16; o <<= 1) mx = fmaxf(mx, __shfl_xor(mx, o, 64));
      float s = 0;
#pragma unroll
      for (int j = 0; j < 8; ++j){ sv[j] = expf(sv[j]-mx); s += sv[j]; }
#pragma unroll
      for (int o = 1; o < 16; o <<= 1) s += __shfl_xor(s, o, 64);
      const float inv = 1.0f/s;
#pragma unroll
      for (int j = 0; j < 8; ++j){
        const int col = j*16 + lr;
        const int slot = (col>>3) ^ (row&7);
        pl[w*4096 + row*128 + slot*8 + (lr&7)] = (__bf16)(sv[j]*inv);
      }
    }
  __syncthreads();
  // PV: O rows w*32+i*16+g*4+r, cols j*16+lr; A = P from pl, B = vt
  f32x4_t acc2[2][8] = {};
#pragma unroll
  for (int ks = 0; ks < 4; ++ks){
    bf16x8_t ap[2], bv[8];
#pragma unroll
    for (int i = 0; i < 2; ++i){
      const int row = i*16 + lr;
      const int slot = (ks*4 + g) ^ (row&7);
      ap[i] = *(bf16x8_t*)&pl[w*4096 + row*128 + slot*8];
    }
#pragma unroll
    for (int j = 0; j < 8; ++j){
      const int rowv = j*16 + lr;
      const int cb = ks*4 + g;
      bv[j] = *(bf16x8_t*)&vt[rowv*128 + ((cb ^ (rowv&7))*8)];
    }
#pragma unroll
    for (int i = 0; i < 2; ++i)
#pragma unroll
      for (int j = 0; j < 8; ++j)
        acc2[i][j] = __builtin_amdgcn_mfma_f32_16x16x32_bf16(ap[i], bv[j], acc2[i][j], 0, 0, 0);
  }
#pragma unroll
  for (int i = 0; i < 2; ++i)
#pragma unroll
    for (int j = 0; j < 8; ++j)
#pragma unroll
      for (int r = 0; r < 4; ++r){
        const int row = w*32 + i*16 + g*4 + r;
        const int col = j*16 + lr;
        O[(size_t)(b*128+row)*1024 + h*128 + col] = (__bf16)acc2[i][j][r];
      }
}

// ------------------------------------------------- final head: out = h @ c2_w.T + c2_b + centers
__global__ __launch_bounds__(256) void c2_kernel(const float* __restrict__ hb,
                                                 const float* __restrict__ w,
                                                 const float* __restrict__ bb,
                                                 const float* __restrict__ centers,
                                                 float* __restrict__ out){
  const int o = blockIdx.x*4 + (threadIdx.x>>6);
  const int lane = threadIdx.x & 63;
  const int tok = o / 96, n = o % 96;
  const float* hp = hb + (size_t)tok*1024;
  const float* wp = w + (size_t)n*1024;
  float s = 0;
#pragma unroll 4
  for (int j = 0; j < 16; ++j){
    int k = lane + j*64;
    s += hp[k] * wp[k];
  }
  s = wredsum(s);
  if (lane == 0) out[o] = s + bb[n] + centers[tok*3 + (n % 3)];
}

// =================================================================
extern "C" void kernel_launch(void* const* d_in, const int* in_sizes, int n_in,
                              void* d_out, int out_size, void* d_ws, size_t ws_size,
                              hipStream_t stream){
  const float* lh   = (const float*)d_in[0];
  const float* pc   = (const float*)d_in[1];
  const float* fpw  = (const float*)d_in[2];
  const float* fpb  = (const float*)d_in[3];
  const float* spw  = (const float*)d_in[4];
  const float* spb  = (const float*)d_in[5];
  const float* pos  = (const float*)d_in[6];
  const float* ln1w = (const float*)d_in[7];
  const float* ln1b = (const float*)d_in[8];
  const float* inw  = (const float*)d_in[9];
  const float* inb  = (const float*)d_in[10];
  const float* outw = (const float*)d_in[11];
  const float* outb = (const float*)d_in[12];
  const float* ln2w = (const float*)d_in[13];
  const float* ln2b = (const float*)d_in[14];
  const float* w1   = (const float*)d_in[15];
  const float* b1   = (const float*)d_in[16];
  const float* w2   = (const float*)d_in[17];
  const float* b2   = (const float*)d_in[18];
  const float* c1w  = (const float*)d_in[19];
  const float* c1b  = (const float*)d_in[20];
  const float* bng  = (const float*)d_in[21];
  const float* bnbt = (const float*)d_in[22];
  const float* bnm  = (const float*)d_in[23];
  const float* bnv  = (const float*)d_in[24];
  const float* c2w  = (const float*)d_in[25];
  const float* c2b  = (const float*)d_in[26];
  float* out = (float*)d_out;

  // ---- workspace layout ----
  float* f = (float*)d_ws;
  float* parts = f;              f += 8*524288;   // split-K fp32 partials (16 MB)
  float* part  = f;              f += 131072;
  float* mlh   = f;              f += 16384;
  float* agg   = f;              f += 4096;
  float* x     = f;              f += 524288;     // residual stream fp32
  float* hc1   = f;              f += 524288;     // c1 out (BN+ReLU) fp32
  float* cent  = f;              f += 2048;       // centers (+pad)
  __bf16* bfp = (__bf16*)f;
  __bf16* xn   = bfp;            bfp += 524288;   // LN out bf16
  __bf16* qkv  = bfp;            bfp += 1572864;
  __bf16* obuf = bfp;            bfp += 524288;
  __bf16* hbf  = bfp;            bfp += 2097152;  // MLP hidden bf16
  __bf16* xbf  = bfp;            bfp += 524288;   // bf16 copy of final x
  __bf16* wbf  = bfp;            bfp += 51380224; // all weights bf16 (4 layers + c1 at +50331648)

  partial_kernel<<<dim3(16,8,4), 256, 0, stream>>>(lh, part);
  combine_kernel<<<64, 256, 0, stream>>>(part, mlh);
  agg_kernel<<<1024, 256, 0, stream>>>(mlh, fpw, fpb, agg);
  fused_front<<<7300, 1024, 0, stream>>>(pc, cent, agg, spw, spb, x,
                                         inw, outw, w1, w2, c1w, wbf);
  ln_kernel<<<512, 256, 0, stream>>>(x, pos, ln1w, ln1b, xn);

  for (int l = 0; l < 4; ++l){
    const __bf16* wl = wbf + (size_t)l*12582912;
    gemm_sk<<<dim3(24,4,2), 256, 0, stream>>>(xn, wl, parts, 512, 3072, 1024, 512);
    comb_qkv<<<6144, 256, 0, stream>>>(parts, inb + l*3072, qkv);
    attn_fused<<<32, 256, 0, stream>>>(qkv, obuf);
    gemm_sk<<<dim3(8,4,8), 256, 0, stream>>>(obuf, wl + 3145728, parts, 512, 1024, 1024, 128);
    comb_res_ln<0><<<512, 256, 0, stream>>>(parts, 8, outb + l*1024, nullptr,
                                            ln2w + l*1024, ln2b + l*1024, x, xn);
    gemm_sk<<<dim3(32,4,2), 256, 0, stream>>>(xn, wl + 4194304, parts, 512, 4096, 1024, 512);
    comb_gelu<<<8192, 256, 0, stream>>>(parts, b1 + l*4096, hbf);
    gemm_sk<<<dim3(8,4,8), 256, 0, stream>>>(hbf, wl + 8388608, parts, 512, 1024, 4096, 512);
    if (l < 3)
      comb_res_ln<1><<<512, 256, 0, stream>>>(parts, 8, b2 + l*1024, pos,
                                              ln1w + (l+1)*1024, ln1b + (l+1)*1024, x, xn);
    else
      comb_res_ln<2><<<512, 256, 0, stream>>>(parts, 8, b2 + l*1024, nullptr,
                                              nullptr, nullptr, x, xbf);
  }

  gemm_sk<<<dim3(8,4,8), 256, 0, stream>>>(xbf, wbf + 50331648, parts, 512, 1024, 1024, 128);
  comb_bn<<<2048, 256, 0, stream>>>(parts, 8, c1b, bnm, bnv, bng, bnbt, hc1);
  c2_kernel<<<12288, 256, 0, stream>>>(hc1, c2w, c2b, cent, out);
}